// Round 12
// baseline (220.906 us; speedup 1.0000x reference)
//
#include <hip/hip_runtime.h>
#include <hip/hip_bf16.h>

// B=2, S=768, H=768, NH=12, D=64, NKEY=9216. Output fp32 [B][S][NH][D].
// Round 19: counted-vmcnt pipeline (T3+T4) in flash. All prior attacks
// (conflicts->0, L2 BW halved, XOR deleted, TLP 2x, FETCH 21->7.4MB via
// XCD swizzle) left flash at ~66us = 26% MfmaUtil -- the m233 2-phase
// signature: stage -> vmcnt(0)-drain barrier -> compute serializes the
// DMA tail with compute every tile. Fix: 3 buffers, 2-ahead prefetch,
// s_waitcnt vmcnt(8) (never 0 mid-loop) + raw s_barrier. Buffer hazards:
// (t+2)%3's last reader is compute(t-1), complete at barrier(t); vmcnt
// retirement is in-order (m135); both waves issue 8 DMA/tile. Compute
// body byte-identical to r16/r18-verified code. Everything else = r18.

typedef __bf16 bf16_t;
typedef __bf16 bf16x8 __attribute__((ext_vector_type(8)));
typedef float f32x4 __attribute__((ext_vector_type(4)));
typedef float f32x16 __attribute__((ext_vector_type(16)));
typedef unsigned long long u64;

#define MFMA16(a, b, c) __builtin_amdgcn_mfma_f32_16x16x32_bf16((a), (b), (c), 0, 0, 0)
#define MFMA32(a, b, c) __builtin_amdgcn_mfma_f32_32x32x16_bf16((a), (b), (c), 0, 0, 0)
#define LOG2E 1.44269504088896340736f
#define SCALE_Q 0.18033688011112042f /* (1/8) * log2(e) */
#define SHIFT_C 8.0f                 /* fixed softmax shift (base-2 units) */
#define NSPLIT 8
#define KCHUNK 1152 /* 9216/8, 18 tiles of 64 */

typedef __attribute__((address_space(3))) unsigned int lds_uint;
typedef const __attribute__((address_space(1))) unsigned int glob_uint;
__device__ __forceinline__ void async_copy16(const void* g, void* l) {
  __builtin_amdgcn_global_load_lds((glob_uint*)g, (lds_uint*)l, 16, 0, 0);
}

// ---------------- transpose + convert: Wt[n][k] = (bf16)W[k][n], 768x768 ----
__global__ __launch_bounds__(256) void transpose_cvt3(const float* __restrict__ Wq,
                                                      const float* __restrict__ Wk,
                                                      const float* __restrict__ Wv,
                                                      bf16_t* __restrict__ Wt) {
  __shared__ float t[32][33];
  const float* W = (blockIdx.z == 0) ? Wq : (blockIdx.z == 1) ? Wk : Wv;
  bf16_t* o = Wt + (size_t)blockIdx.z * 589824;
  const int bx = blockIdx.x * 32;
  const int by = blockIdx.y * 32;
  const int tx = threadIdx.x, ty = threadIdx.y;
#pragma unroll
  for (int i = 0; i < 32; i += 8) t[ty + i][tx] = W[(bx + ty + i) * 768 + by + tx];
  __syncthreads();
#pragma unroll
  for (int i = 0; i < 32; i += 8)
    o[(by + ty + i) * 768 + bx + tx] = (bf16_t)t[tx][ty + i];
}

// ---------------- canonical C[M][N] = A[M][K] * B[N][K]^T, bf16 MFMA --------
__device__ __forceinline__ bf16x8 cvt8u(const uint4 x, const uint4 y) {
  union { uint4 u; float f[4]; } a, b;
  a.u = x; b.u = y;
  bf16x8 o;
  o[0] = (bf16_t)a.f[0]; o[1] = (bf16_t)a.f[1];
  o[2] = (bf16_t)a.f[2]; o[3] = (bf16_t)a.f[3];
  o[4] = (bf16_t)b.f[0]; o[5] = (bf16_t)b.f[1];
  o[6] = (bf16_t)b.f[2]; o[7] = (bf16_t)b.f[3];
  return o;
}

// Double-buffered LDS, one barrier per 64-deep K slab, register prefetch.
template <int BM, int BN, bool AF32, bool BF32, typename EPI>
__device__ __forceinline__ void gemm_core(char* __restrict__ smem,
                                          const void* __restrict__ Ap, int lda,
                                          const void* __restrict__ Bp, int ldb,
                                          int K, int m0, int n0, EPI epi) {
  constexpr int MT = BM / 32;
  constexpr int NT = BN / 32;
  constexpr int AC = BM * 8 / 256;  // 16B chunks per thread (A)
  constexpr int BC = BN * 8 / 256;
  constexpr int HALF = (BM + BN) * 144;

  const int tid = threadIdx.x;
  const int lane = tid & 63;
  const int w = tid >> 6;
  const int l15 = lane & 15, quad = lane >> 4;
  const int wm = (w & 1) * (BM / 2);
  const int wn = (w >> 1) * (BN / 2);

  uint4 pa[AC][2], pb[BC][2];

  auto loadA = [&](int kk) {
#pragma unroll
    for (int i = 0; i < AC; ++i) {
      const int cidx = tid + i * 256, r = cidx >> 3, ch = cidx & 7;
      if constexpr (AF32) {
        const float* s = (const float*)Ap + (size_t)(m0 + r) * lda + kk + ch * 8;
        pa[i][0] = *(const uint4*)s;
        pa[i][1] = *(const uint4*)(s + 4);
      } else {
        const bf16_t* s = (const bf16_t*)Ap + (size_t)(m0 + r) * lda + kk + ch * 8;
        pa[i][0] = *(const uint4*)s;
      }
    }
  };
  auto loadB = [&](int kk) {
#pragma unroll
    for (int i = 0; i < BC; ++i) {
      const int cidx = tid + i * 256, r = cidx >> 3, ch = cidx & 7;
      if constexpr (BF32) {
        const float* s = (const float*)Bp + (size_t)(n0 + r) * ldb + kk + ch * 8;
        pb[i][0] = *(const uint4*)s;
        pb[i][1] = *(const uint4*)(s + 4);
      } else {
        const bf16_t* s = (const bf16_t*)Bp + (size_t)(n0 + r) * ldb + kk + ch * 8;
        pb[i][0] = *(const uint4*)s;
      }
    }
  };
  auto store = [&](char* base) {
    char* sA = base;
    char* sB = base + BM * 144;
#pragma unroll
    for (int i = 0; i < AC; ++i) {
      const int cidx = tid + i * 256, r = cidx >> 3, ch = cidx & 7;
      if constexpr (AF32)
        *(bf16x8*)(sA + r * 144 + ch * 16) = cvt8u(pa[i][0], pa[i][1]);
      else
        *(uint4*)(sA + r * 144 + ch * 16) = pa[i][0];
    }
#pragma unroll
    for (int i = 0; i < BC; ++i) {
      const int cidx = tid + i * 256, r = cidx >> 3, ch = cidx & 7;
      if constexpr (BF32)
        *(bf16x8*)(sB + r * 144 + ch * 16) = cvt8u(pb[i][0], pb[i][1]);
      else
        *(uint4*)(sB + r * 144 + ch * 16) = pb[i][0];
    }
  };

  const f32x4 fzero = {0.f, 0.f, 0.f, 0.f};
  f32x4 acc[MT][NT];
#pragma unroll
  for (int i = 0; i < MT; ++i)
#pragma unroll
    for (int j = 0; j < NT; ++j) acc[i][j] = fzero;

  const int NS = K / 64;
  loadA(0);
  loadB(0);
  store(smem);

  for (int t = 0; t < NS; ++t) {
    char* base = smem + (t & 1) * HALF;
    char* sA = base;
    char* sB = base + BM * 144;
    __syncthreads();
    if (t + 1 < NS) {
      loadA((t + 1) * 64);
      loadB((t + 1) * 64);
    }
#pragma unroll
    for (int ks = 0; ks < 2; ++ks) {
      bf16x8 af[MT], bfr[NT];
#pragma unroll
      for (int i = 0; i < MT; ++i)
        af[i] = *(const bf16x8*)(sA + (wm + i * 16 + l15) * 144 + ks * 64 + quad * 16);
#pragma unroll
      for (int j = 0; j < NT; ++j)
        bfr[j] = *(const bf16x8*)(sB + (wn + j * 16 + l15) * 144 + ks * 64 + quad * 16);
#pragma unroll
      for (int i = 0; i < MT; ++i)
#pragma unroll
        for (int j = 0; j < NT; ++j) acc[i][j] = MFMA16(af[i], bfr[j], acc[i][j]);
    }
    if (t + 1 < NS) store(smem + ((t + 1) & 1) * HALF);
  }
#pragma unroll
  for (int i = 0; i < MT; ++i)
#pragma unroll
    for (int j = 0; j < NT; ++j)
#pragma unroll
      for (int p = 0; p < 4; ++p)
        epi(m0 + wm + i * 16 + quad * 4 + p, n0 + wn + j * 16 + l15, acc[i][j][p]);
}

// Merged QKV projections (128x64 tiles, dbuf).
__global__ __launch_bounds__(256) void gemm_qkv(const float* __restrict__ hid,
                                                const bf16_t* __restrict__ wT,
                                                const float* __restrict__ bq,
                                                const float* __restrict__ bk,
                                                const float* __restrict__ bv,
                                                bf16_t* __restrict__ q,
                                                bf16_t* __restrict__ ktvt) {
  __shared__ __align__(16) char smem[2 * (128 + 64) * 144];
  if (blockIdx.y < 12) {
    const int m0 = blockIdx.x * 128, n0 = blockIdx.y * 64;
    auto epi = [=](int m, int n, float v) {
      const int b = m / 768, s = m - b * 768;
      const int h = n >> 6, d = n & 63;
      q[((size_t)((b * 12 + h) * 768 + s) << 6) + d] = (bf16_t)((v + bq[n]) * SCALE_Q);
    };
    gemm_core<128, 64, true, false>(smem, hid, 768, wT, 768, 768, m0, n0, epi);
  } else {
    const int m0 = blockIdx.x * 128, n0 = (blockIdx.y - 12) * 64;
    auto epi = [=](int m, int n, float v) {
      const float bias = (m < 768) ? bk[m] : bv[m - 768];
      ktvt[(size_t)m * 1536 + n] = (bf16_t)(v + bias);
    };
    gemm_core<128, 64, false, true>(smem, wT + 589824, 768, hid, 768, 768, m0, n0, epi);
  }
}

// Merged memory GEMMs (128x64 / 64x128 tiles, dbuf). BOTH outputs
// FRAGMENT-MAJOR (r8/r16-verified layouts; consumed by linear DMA + LDS):
//  kcF:  elem = ((T*2+mb)*4+kd)*512 + (h5*32+l31)*8 + j
//  vctF: elem = (((T*2+mb)*2+tt)*2+md)*512 + (h5*32+l31)*8 + u*4+j
// A 64-key tile T is a contiguous 8KB block in each.
__global__ __launch_bounds__(256) void gemm_mem(const float* __restrict__ memk,
                                                const float* __restrict__ memv,
                                                const bf16_t* __restrict__ ktvt,
                                                bf16_t* __restrict__ kc,
                                                bf16_t* __restrict__ vct) {
  __shared__ __align__(16) char smem[2 * (128 + 64) * 144];
  const int z = blockIdx.z, b = z / 12, h = z - (z / 12) * 12;
  if (blockIdx.y == 0) {
    const int m0 = blockIdx.x * 128;
    const float* A = memk + (size_t)h * 589824;
    const bf16_t* B = ktvt + (size_t)(h * 64) * 1536 + b * 768;
    bf16_t* outp = kc + (size_t)b * 589824;
    auto epi = [=](int m, int n, float v) {
      const int gk = h * 768 + m;  // global key index
      const int T = gk >> 6, mbk = (gk >> 5) & 1, l31k = gk & 31;
      const int kd = n >> 4, hh = (n >> 3) & 1, j = n & 7;
      outp[(((size_t)(T * 2 + mbk) * 4 + kd) << 9) + ((hh * 32 + l31k) << 3) + j] =
          (bf16_t)v;
    };
    gemm_core<128, 64, true, false>(smem, A, 768, B, 1536, 768, m0, 0, epi);
  } else {
    const int n0 = blockIdx.x * 128;
    const bf16_t* A = ktvt + (size_t)(768 + h * 64) * 1536 + b * 768;
    const float* B = memv + (size_t)h * 589824;
    bf16_t* outp = vct + (size_t)b * 589824;
    auto epi = [=](int m, int n, float v) {
      const int gk = h * 768 + n;  // global key index, m = d
      const int T = gk >> 6, mbv = (gk >> 5) & 1, tt = (gk >> 4) & 1;
      const int u = (gk >> 3) & 1, hh = (gk >> 2) & 1, j = gk & 3;
      const int md = m >> 5, l31v = m & 31;
      outp[((((size_t)(T * 2 + mbv) * 2 + tt) * 2 + md) << 9) +
           ((hh * 32 + l31v) << 3) + u * 4 + j] = (bf16_t)v;
    };
    gemm_core<64, 128, false, true>(smem, A, 1536, B, 768, 768, 0, n0, epi);
  }
}

// ---------------- flash attention, split-K, 32x32 MFMA, transposed-S -------
// 128-thread blocks (2 waves x 64 q-rows). 1-D grid 1152, XCD-affinity
// swizzle (r18-verified: FETCH 21->7.4MB). K/V fragment-major, tile T =
// contiguous 8KB. TRIPLE-buffered linear DMA staging with COUNTED vmcnt:
// per tile: s_waitcnt vmcnt(8) [own tile-t loads retired; tile-t+1's 8
// stay in flight -- never drain to 0 mid-loop] -> s_barrier -> issue
// stage(t+2) -> compute(t). Buffer (t+2)%3's last reader is compute(t-1),
// complete at barrier(t) for both waves. Mask weights in LDS (lgkmcnt(0)
// before first barrier). Compute body byte-identical to verified r16.
__global__ __launch_bounds__(128, 2) void flash_attn_split(
    const bf16_t* __restrict__ q, const bf16_t* __restrict__ kc,
    const bf16_t* __restrict__ vct, const float* __restrict__ mask,
    float* __restrict__ part_acc, float* __restrict__ part_l) {
  // XCD-affinity decode (1152 = 8 XCDs x 144 logical slots)
  const int bid = blockIdx.x;
  const int logical = (bid & 7) * 144 + (bid >> 3);
  const int z = logical / 72;        // 0..15, z-major: 2 chunks per XCD
  const int rem = logical - z * 72;  // 0..71
  const int h = rem / 6;
  const int qt = rem - h * 6;
  const int b = z >> 3, c = z & 7;

  const int tid = threadIdx.x;
  const int w = tid >> 6, lane = tid & 63, l31 = lane & 31, h5 = lane >> 5;

  __shared__ __align__(16) bf16_t kc_s[3][64 * 64];  // K tbuf, fragment-major
  __shared__ __align__(16) bf16_t vt_s[3][64 * 64];  // V tbuf, fragment-major
  __shared__ float w_all[KCHUNK];                    // additive mask (log2)

  const bf16_t* kcb = kc + (size_t)b * 589824;
  const bf16_t* vtb = vct + (size_t)b * 589824;
  const float* mkb = mask + b * 9216;
  const int k00 = c * KCHUNK;
  const int T0 = c * (KCHUNK / 64);  // global 64-key tile index base
  constexpr int NT = KCHUNK / 64;    // 18

  // Q B-frags, held for the whole kernel
  const int q0 = qt * 128 + w * 64;
  bf16x8 qf[2][4];
#pragma unroll
  for (int nb = 0; nb < 2; ++nb) {
    const bf16_t* qp =
        q + ((size_t)((b * 12 + h) * 768 + q0 + nb * 32 + l31) << 6) + h5 * 8;
#pragma unroll
    for (int kd = 0; kd < 4; ++kd) qf[nb][kd] = *(const bf16x8*)(qp + kd * 16);
  }

  // additive mask weights for the whole 1152-key chunk, once
  for (int i = tid; i < KCHUNK; i += 128)
    w_all[i] = fmaf(mkb[k00 + i], LOG2E, -SHIFT_C);

  // linear DMA staging: wave 0 -> K tile, wave 1 -> V tile (8x 1KB each)
  auto stage = [&](int t, int buf) {
    const int T = T0 + t;
    const char* ksrc = (const char*)(kcb + ((size_t)T << 12));
    const char* vsrc = (const char*)(vtb + ((size_t)T << 12));
#pragma unroll
    for (int i = 0; i < 8; ++i) {
      const int off = (i * 64 + lane) * 16;  // byte offset 0..8191
      if (w == 0)
        async_copy16(ksrc + off, (char*)&kc_s[buf][0] + off);
      else
        async_copy16(vsrc + off, (char*)&vt_s[buf][0] + off);
    }
  };

  stage(0, 0);
  stage(1, 1);
  // own w_all ds_writes drained before first barrier (mutual visibility)
  asm volatile("s_waitcnt lgkmcnt(0)" ::: "memory");

  f32x16 o[2][2];
#pragma unroll
  for (int nb = 0; nb < 2; ++nb)
#pragma unroll
    for (int md = 0; md < 2; ++md)
#pragma unroll
      for (int r = 0; r < 16; ++r) o[nb][md][r] = 0.f;
  float rsum[2] = {0.f, 0.f};

  const int lb = lane << 4;  // per-lane byte offset within a fragment

  for (int t = 0; t < NT; ++t) {
    // wait own tile-t DMAs retired; keep tile-t+1's 8 in flight
    if (t + 1 < NT)
      asm volatile("s_waitcnt vmcnt(8)" ::: "memory");
    else
      asm volatile("s_waitcnt vmcnt(0)" ::: "memory");
    __builtin_amdgcn_s_barrier();
    if (t + 2 < NT) stage(t + 2, (t + 2) % 3);

    const char* kcS = (const char*)&kc_s[t % 3][0];
    const char* vtS = (const char*)&vt_s[t % 3][0];
    const float* wt = w_all + t * 64;

#pragma unroll
    for (int mb = 0; mb < 2; ++mb) {  // 32-key block
      bf16x8 ka[4];
#pragma unroll
      for (int kd = 0; kd < 4; ++kd)
        ka[kd] = *(const bf16x8*)(kcS + ((mb * 4 + kd) << 10) + lb);
      bf16x8 va[2][2];
#pragma unroll
      for (int md = 0; md < 2; ++md)
#pragma unroll
        for (int tt = 0; tt < 2; ++tt)
          va[md][tt] = *(const bf16x8*)(vtS + (((mb * 2 + tt) * 2 + md) << 10) + lb);
      float wv[16];
#pragma unroll
      for (int g = 0; g < 4; ++g) {
        const float4 t4 = *(const float4*)(wt + mb * 32 + h5 * 4 + g * 8);
        wv[g * 4 + 0] = t4.x; wv[g * 4 + 1] = t4.y;
        wv[g * 4 + 2] = t4.z; wv[g * 4 + 3] = t4.w;
      }
#pragma unroll
      for (int nb = 0; nb < 2; ++nb) {
        f32x16 s;
#pragma unroll
        for (int r = 0; r < 16; ++r) s[r] = wv[r];  // mask folded into acc init
#pragma unroll
        for (int kd = 0; kd < 4; ++kd) s = MFMA32(ka[kd], qf[nb][kd], s);
        bf16x8 pb0, pb1;
#pragma unroll
        for (int r = 0; r < 8; ++r) {
          const float pv = __builtin_amdgcn_exp2f(s[r]);
          rsum[nb] += pv;
          pb0[r] = (bf16_t)pv;
        }
#pragma unroll
        for (int r = 0; r < 8; ++r) {
          const float pv = __builtin_amdgcn_exp2f(s[8 + r]);
          rsum[nb] += pv;
          pb1[r] = (bf16_t)pv;
        }
#pragma unroll
        for (int md = 0; md < 2; ++md) {
          o[nb][md] = MFMA32(va[md][0], pb0, o[nb][md]);
          o[nb][md] = MFMA32(va[md][1], pb1, o[nb][md]);
        }
      }
    }
  }

  const float l0 = rsum[0] + __shfl_xor(rsum[0], 32);
  const float l1 = rsum[1] + __shfl_xor(rsum[1], 32);

  const int pidx = ((b * 12 + h) * 6 + qt) * NSPLIT + c;
  float* pacc = part_acc + (size_t)pidx * 8192;
#pragma unroll
  for (int nb = 0; nb < 2; ++nb) {
    const int ql = w * 64 + nb * 32 + l31;
#pragma unroll
    for (int md = 0; md < 2; ++md)
#pragma unroll
      for (int g = 0; g < 4; ++g) {
        float4 v;
        v.x = o[nb][md][g * 4 + 0];
        v.y = o[nb][md][g * 4 + 1];
        v.z = o[nb][md][g * 4 + 2];
        v.w = o[nb][md][g * 4 + 3];
        *(float4*)(pacc + (size_t)ql * 64 + md * 32 + h5 * 4 + g * 8) = v;
      }
  }
  if (h5 == 0) {
    part_l[(size_t)pidx * 128 + w * 64 + l31] = l0;
    part_l[(size_t)pidx * 128 + w * 64 + 32 + l31] = l1;
  }
}

// ---------------- combine split-K partials, normalize, gate, write out -----
// 576 blocks x 256 threads: each block handles 32 q-rows. Pure-BW kernel.
__global__ __launch_bounds__(256) void flash_combine(
    const float* __restrict__ part_acc, const float* __restrict__ part_l,
    const float* __restrict__ gate, float* __restrict__ out) {
  const int q32 = blockIdx.x, h = blockIdx.y, b = blockIdx.z;  // grid (24,12,2)
  const int tid = threadIdx.x;
  const int row = tid >> 3, dseg = tid & 7;  // 32 rows, 8 d-elems per thread
  const int s = q32 * 32 + row;              // global q-row 0..767
  const int qt = s >> 7;                     // 128-row part tile
  const int roff = s & 127;
  const int base = ((b * 12 + h) * 6 + qt) * NSPLIT;

  float L = 0.f;
#pragma unroll
  for (int ci = 0; ci < NSPLIT; ++ci) L += part_l[(size_t)(base + ci) * 128 + roff];

  f32x4 a0 = {0.f, 0.f, 0.f, 0.f}, a1 = {0.f, 0.f, 0.f, 0.f};
#pragma unroll
  for (int ci = 0; ci < NSPLIT; ++ci) {
    const float* p = part_acc + (size_t)(base + ci) * 8192 + roff * 64 + dseg * 8;
    const float4 v0 = *(const float4*)p;
    const float4 v1 = *(const float4*)(p + 4);
    a0[0] += v0.x; a0[1] += v0.y; a0[2] += v0.z; a0[3] += v0.w;
    a1[0] += v1.x; a1[1] += v1.y; a1[2] += v1.z; a1[3] += v1.w;
  }
  const float g = 1.f / (1.f + expf(-gate[h]));
  const float sc = g / L;
  float* op = out + ((size_t)((b * 768 + s) * 12 + h) << 6) + dseg * 8;
  float4 w0, w1;
  w0.x = a0[0] * sc; w0.y = a0[1] * sc; w0.z = a0[2] * sc; w0.w = a0[3] * sc;
  w1.x = a1[0] * sc; w1.y = a1[1] * sc; w1.z = a1[2] * sc; w1.w = a1[3] * sc;
  *(float4*)op = w0;
  *(float4*)(op + 4) = w1;
}

extern "C" void kernel_launch(void* const* d_in, const int* in_sizes, int n_in,
                              void* d_out, int out_size, void* d_ws, size_t ws_size,
                              hipStream_t stream) {
  const float* hid  = (const float*)d_in[0];
  const float* mask = (const float*)d_in[1];
  const float* Wq   = (const float*)d_in[2];
  const float* bq   = (const float*)d_in[3];
  const float* Wk   = (const float*)d_in[4];
  const float* bk   = (const float*)d_in[5];
  const float* Wv   = (const float*)d_in[6];
  const float* bv   = (const float*)d_in[7];
  const float* gate = (const float*)d_in[8];
  const float* memk = (const float*)d_in[9];
  const float* memv = (const float*)d_in[10];
  float* out = (float*)d_out;

  // workspace layout (~53.7 MB total)
  char* ws = (char*)d_ws;
  bf16_t* wqkvT    = (bf16_t*)(ws);             // [2304][768] bf16
  bf16_t* qb       = (bf16_t*)(ws + 3538944);   // q [2][12][768][64] bf16
  bf16_t* ktvt     = (bf16_t*)(ws + 5898240);   // [1536][1536] bf16
  bf16_t* kcw      = (bf16_t*)(ws + 10616832);  // kc fragment-major, per b
  bf16_t* vct      = (bf16_t*)(ws + 12976128);  // vc^T fragment-major, per b
  float*  part_acc = (float*)(ws + 15335424);   // [1152][128][64] fp32
  float*  part_l   = (float*)(ws + 53084160);   // [1152][128] fp32

  transpose_cvt3<<<dim3(24, 24, 3), dim3(32, 8), 0, stream>>>(Wq, Wk, Wv, wqkvT);
  gemm_qkv<<<dim3(12, 36), 256, 0, stream>>>(hid, wqkvT, bq, bk, bv, qb, ktvt);
  gemm_mem<<<dim3(6, 2, 24), 256, 0, stream>>>(memk, memv, ktvt, kcw, vct);
  flash_attn_split<<<dim3(1152), 128, 0, stream>>>(qb, kcw, vct, mask,
                                                   part_acc, part_l);
  flash_combine<<<dim3(24, 12, 2), 256, 0, stream>>>(part_acc, part_l, gate, out);
}

// Round 13
// 212.826 us; speedup vs baseline: 1.0380x; 1.0380x over previous
//
#include <hip/hip_runtime.h>
#include <hip/hip_bf16.h>

// B=2, S=768, H=768, NH=12, D=64, NKEY=9216. Output fp32 [B][S][NH][D].
// Round 20: flash reverted to r18 verbatim (65.7us verified: K+V fragment-
// major linear DMA dbuf, XCD-affinity swizzle, 2-buffer, (128,2)); r19's
// counted-vmcnt 3-buffer cut occupancy (LDS 52.5KB -> 3 blocks/CU) and
// regressed -- flash declared at structural floor. This round attacks the
// ~145us periphery (~110us = the two GEMM kernels): new cvt_inputs kernel
// converts hid/mem_keys/mem_values fp32->bf16 once (outputs aliased into
// the part_acc region, dead until flash); gemm_qkv/gemm_mem become
// all-bf16 (staging bytes halved, all cvt8u VALU deleted, gemm_mem HBM
// reads 113->56MB). Epilogues/tiles/grids unchanged.

typedef __bf16 bf16_t;
typedef __bf16 bf16x4 __attribute__((ext_vector_type(4)));
typedef __bf16 bf16x8 __attribute__((ext_vector_type(8)));
typedef float f32x4 __attribute__((ext_vector_type(4)));
typedef float f32x16 __attribute__((ext_vector_type(16)));
typedef unsigned long long u64;

#define MFMA16(a, b, c) __builtin_amdgcn_mfma_f32_16x16x32_bf16((a), (b), (c), 0, 0, 0)
#define MFMA32(a, b, c) __builtin_amdgcn_mfma_f32_32x32x16_bf16((a), (b), (c), 0, 0, 0)
#define LOG2E 1.44269504088896340736f
#define SCALE_Q 0.18033688011112042f /* (1/8) * log2(e) */
#define SHIFT_C 8.0f                 /* fixed softmax shift (base-2 units) */
#define NSPLIT 8
#define KCHUNK 1152 /* 9216/8, 18 tiles of 64 */

typedef __attribute__((address_space(3))) unsigned int lds_uint;
typedef const __attribute__((address_space(1))) unsigned int glob_uint;
__device__ __forceinline__ void async_copy16(const void* g, void* l) {
  __builtin_amdgcn_global_load_lds((glob_uint*)g, (lds_uint*)l, 16, 0, 0);
}

// ---------------- transpose + convert: Wt[n][k] = (bf16)W[k][n], 768x768 ----
__global__ __launch_bounds__(256) void transpose_cvt3(const float* __restrict__ Wq,
                                                      const float* __restrict__ Wk,
                                                      const float* __restrict__ Wv,
                                                      bf16_t* __restrict__ Wt) {
  __shared__ float t[32][33];
  const float* W = (blockIdx.z == 0) ? Wq : (blockIdx.z == 1) ? Wk : Wv;
  bf16_t* o = Wt + (size_t)blockIdx.z * 589824;
  const int bx = blockIdx.x * 32;
  const int by = blockIdx.y * 32;
  const int tx = threadIdx.x, ty = threadIdx.y;
#pragma unroll
  for (int i = 0; i < 32; i += 8) t[ty + i][tx] = W[(bx + ty + i) * 768 + by + tx];
  __syncthreads();
#pragma unroll
  for (int i = 0; i < 32; i += 8)
    o[(by + ty + i) * 768 + bx + tx] = (bf16_t)t[tx][ty + i];
}

// ---------------- fp32 -> bf16 input conversion (hid, mem_keys, mem_values) -
__global__ __launch_bounds__(256) void cvt_inputs(const float* __restrict__ hid,
                                                  const float* __restrict__ memk,
                                                  const float* __restrict__ memv,
                                                  bf16_t* __restrict__ hidb,
                                                  bf16_t* __restrict__ memkb,
                                                  bf16_t* __restrict__ memvb) {
  const int NH4 = 1179648 / 4;    // hid float4 count
  const int NM4 = 7077888 / 4;    // memk/memv float4 count
  const int TOT = NH4 + 2 * NM4;  // 3833856
  for (int i = blockIdx.x * 256 + threadIdx.x; i < TOT; i += gridDim.x * 256) {
    const float* s;
    bf16_t* d;
    int off;
    if (i < NH4) {
      s = hid; d = hidb; off = i;
    } else if (i < NH4 + NM4) {
      s = memk; d = memkb; off = i - NH4;
    } else {
      s = memv; d = memvb; off = i - NH4 - NM4;
    }
    const float4 v = *(const float4*)(s + (size_t)off * 4);
    bf16x4 o;
    o[0] = (bf16_t)v.x; o[1] = (bf16_t)v.y;
    o[2] = (bf16_t)v.z; o[3] = (bf16_t)v.w;
    *(bf16x4*)(d + (size_t)off * 4) = o;
  }
}

// ---------------- canonical C[M][N] = A[M][K] * B[N][K]^T, bf16 MFMA --------
__device__ __forceinline__ bf16x8 cvt8u(const uint4 x, const uint4 y) {
  union { uint4 u; float f[4]; } a, b;
  a.u = x; b.u = y;
  bf16x8 o;
  o[0] = (bf16_t)a.f[0]; o[1] = (bf16_t)a.f[1];
  o[2] = (bf16_t)a.f[2]; o[3] = (bf16_t)a.f[3];
  o[4] = (bf16_t)b.f[0]; o[5] = (bf16_t)b.f[1];
  o[6] = (bf16_t)b.f[2]; o[7] = (bf16_t)b.f[3];
  return o;
}

// Double-buffered LDS, one barrier per 64-deep K slab, register prefetch.
template <int BM, int BN, bool AF32, bool BF32, typename EPI>
__device__ __forceinline__ void gemm_core(char* __restrict__ smem,
                                          const void* __restrict__ Ap, int lda,
                                          const void* __restrict__ Bp, int ldb,
                                          int K, int m0, int n0, EPI epi) {
  constexpr int MT = BM / 32;
  constexpr int NT = BN / 32;
  constexpr int AC = BM * 8 / 256;  // 16B chunks per thread (A)
  constexpr int BC = BN * 8 / 256;
  constexpr int HALF = (BM + BN) * 144;

  const int tid = threadIdx.x;
  const int lane = tid & 63;
  const int w = tid >> 6;
  const int l15 = lane & 15, quad = lane >> 4;
  const int wm = (w & 1) * (BM / 2);
  const int wn = (w >> 1) * (BN / 2);

  uint4 pa[AC][2], pb[BC][2];

  auto loadA = [&](int kk) {
#pragma unroll
    for (int i = 0; i < AC; ++i) {
      const int cidx = tid + i * 256, r = cidx >> 3, ch = cidx & 7;
      if constexpr (AF32) {
        const float* s = (const float*)Ap + (size_t)(m0 + r) * lda + kk + ch * 8;
        pa[i][0] = *(const uint4*)s;
        pa[i][1] = *(const uint4*)(s + 4);
      } else {
        const bf16_t* s = (const bf16_t*)Ap + (size_t)(m0 + r) * lda + kk + ch * 8;
        pa[i][0] = *(const uint4*)s;
      }
    }
  };
  auto loadB = [&](int kk) {
#pragma unroll
    for (int i = 0; i < BC; ++i) {
      const int cidx = tid + i * 256, r = cidx >> 3, ch = cidx & 7;
      if constexpr (BF32) {
        const float* s = (const float*)Bp + (size_t)(n0 + r) * ldb + kk + ch * 8;
        pb[i][0] = *(const uint4*)s;
        pb[i][1] = *(const uint4*)(s + 4);
      } else {
        const bf16_t* s = (const bf16_t*)Bp + (size_t)(n0 + r) * ldb + kk + ch * 8;
        pb[i][0] = *(const uint4*)s;
      }
    }
  };
  auto store = [&](char* base) {
    char* sA = base;
    char* sB = base + BM * 144;
#pragma unroll
    for (int i = 0; i < AC; ++i) {
      const int cidx = tid + i * 256, r = cidx >> 3, ch = cidx & 7;
      if constexpr (AF32)
        *(bf16x8*)(sA + r * 144 + ch * 16) = cvt8u(pa[i][0], pa[i][1]);
      else
        *(uint4*)(sA + r * 144 + ch * 16) = pa[i][0];
    }
#pragma unroll
    for (int i = 0; i < BC; ++i) {
      const int cidx = tid + i * 256, r = cidx >> 3, ch = cidx & 7;
      if constexpr (BF32)
        *(bf16x8*)(sB + r * 144 + ch * 16) = cvt8u(pb[i][0], pb[i][1]);
      else
        *(uint4*)(sB + r * 144 + ch * 16) = pb[i][0];
    }
  };

  const f32x4 fzero = {0.f, 0.f, 0.f, 0.f};
  f32x4 acc[MT][NT];
#pragma unroll
  for (int i = 0; i < MT; ++i)
#pragma unroll
    for (int j = 0; j < NT; ++j) acc[i][j] = fzero;

  const int NS = K / 64;
  loadA(0);
  loadB(0);
  store(smem);

  for (int t = 0; t < NS; ++t) {
    char* base = smem + (t & 1) * HALF;
    char* sA = base;
    char* sB = base + BM * 144;
    __syncthreads();
    if (t + 1 < NS) {
      loadA((t + 1) * 64);
      loadB((t + 1) * 64);
    }
#pragma unroll
    for (int ks = 0; ks < 2; ++ks) {
      bf16x8 af[MT], bfr[NT];
#pragma unroll
      for (int i = 0; i < MT; ++i)
        af[i] = *(const bf16x8*)(sA + (wm + i * 16 + l15) * 144 + ks * 64 + quad * 16);
#pragma unroll
      for (int j = 0; j < NT; ++j)
        bfr[j] = *(const bf16x8*)(sB + (wn + j * 16 + l15) * 144 + ks * 64 + quad * 16);
#pragma unroll
      for (int i = 0; i < MT; ++i)
#pragma unroll
        for (int j = 0; j < NT; ++j) acc[i][j] = MFMA16(af[i], bfr[j], acc[i][j]);
    }
    if (t + 1 < NS) store(smem + ((t + 1) & 1) * HALF);
  }
#pragma unroll
  for (int i = 0; i < MT; ++i)
#pragma unroll
    for (int j = 0; j < NT; ++j)
#pragma unroll
      for (int p = 0; p < 4; ++p)
        epi(m0 + wm + i * 16 + quad * 4 + p, n0 + wn + j * 16 + l15, acc[i][j][p]);
}

// Merged QKV projections (128x64 tiles, dbuf, all-bf16 operands).
__global__ __launch_bounds__(256) void gemm_qkv(const bf16_t* __restrict__ hidb,
                                                const bf16_t* __restrict__ wT,
                                                const float* __restrict__ bq,
                                                const float* __restrict__ bk,
                                                const float* __restrict__ bv,
                                                bf16_t* __restrict__ q,
                                                bf16_t* __restrict__ ktvt) {
  __shared__ __align__(16) char smem[2 * (128 + 64) * 144];
  if (blockIdx.y < 12) {
    const int m0 = blockIdx.x * 128, n0 = blockIdx.y * 64;
    auto epi = [=](int m, int n, float v) {
      const int b = m / 768, s = m - b * 768;
      const int h = n >> 6, d = n & 63;
      q[((size_t)((b * 12 + h) * 768 + s) << 6) + d] = (bf16_t)((v + bq[n]) * SCALE_Q);
    };
    gemm_core<128, 64, false, false>(smem, hidb, 768, wT, 768, 768, m0, n0, epi);
  } else {
    const int m0 = blockIdx.x * 128, n0 = (blockIdx.y - 12) * 64;
    auto epi = [=](int m, int n, float v) {
      const float bias = (m < 768) ? bk[m] : bv[m - 768];
      ktvt[(size_t)m * 1536 + n] = (bf16_t)(v + bias);
    };
    gemm_core<128, 64, false, false>(smem, wT + 589824, 768, hidb, 768, 768, m0, n0, epi);
  }
}

// Merged memory GEMMs (128x64 / 64x128 tiles, dbuf, all-bf16 operands).
// BOTH outputs FRAGMENT-MAJOR (r8/r16-verified layouts):
//  kcF:  elem = ((T*2+mb)*4+kd)*512 + (h5*32+l31)*8 + j
//  vctF: elem = (((T*2+mb)*2+tt)*2+md)*512 + (h5*32+l31)*8 + u*4+j
// A 64-key tile T is a contiguous 8KB block in each.
__global__ __launch_bounds__(256) void gemm_mem(const bf16_t* __restrict__ memkb,
                                                const bf16_t* __restrict__ memvb,
                                                const bf16_t* __restrict__ ktvt,
                                                bf16_t* __restrict__ kc,
                                                bf16_t* __restrict__ vct) {
  __shared__ __align__(16) char smem[2 * (128 + 64) * 144];
  const int z = blockIdx.z, b = z / 12, h = z - (z / 12) * 12;
  if (blockIdx.y == 0) {
    const int m0 = blockIdx.x * 128;
    const bf16_t* A = memkb + (size_t)h * 589824;
    const bf16_t* B = ktvt + (size_t)(h * 64) * 1536 + b * 768;
    bf16_t* outp = kc + (size_t)b * 589824;
    auto epi = [=](int m, int n, float v) {
      const int gk = h * 768 + m;  // global key index
      const int T = gk >> 6, mbk = (gk >> 5) & 1, l31k = gk & 31;
      const int kd = n >> 4, hh = (n >> 3) & 1, j = n & 7;
      outp[(((size_t)(T * 2 + mbk) * 4 + kd) << 9) + ((hh * 32 + l31k) << 3) + j] =
          (bf16_t)v;
    };
    gemm_core<128, 64, false, false>(smem, A, 768, B, 1536, 768, m0, 0, epi);
  } else {
    const int n0 = blockIdx.x * 128;
    const bf16_t* A = ktvt + (size_t)(768 + h * 64) * 1536 + b * 768;
    const bf16_t* B = memvb + (size_t)h * 589824;
    bf16_t* outp = vct + (size_t)b * 589824;
    auto epi = [=](int m, int n, float v) {
      const int gk = h * 768 + n;  // global key index, m = d
      const int T = gk >> 6, mbv = (gk >> 5) & 1, tt = (gk >> 4) & 1;
      const int u = (gk >> 3) & 1, hh = (gk >> 2) & 1, j = gk & 3;
      const int md = m >> 5, l31v = m & 31;
      outp[((((size_t)(T * 2 + mbv) * 2 + tt) * 2 + md) << 9) +
           ((hh * 32 + l31v) << 3) + u * 4 + j] = (bf16_t)v;
    };
    gemm_core<64, 128, false, false>(smem, A, 1536, B, 768, 768, 0, n0, epi);
  }
}

// ---------------- flash attention, split-K, 32x32 MFMA, transposed-S -------
// r18 VERBATIM (65.7us verified). 128-thread blocks (2 waves x 64 q-rows).
// 1-D grid 1152 with XCD-affinity swizzle (FETCH 21->7.4MB). K/V fragment-
// major: tile T = contiguous 8KB, staged via LINEAR global_load_lds DMA
// double-buffer (wave 0 -> K, wave 1 -> V; 8x 1KB). LDS fragment reads at
// frag*1KB + lane*16: conflict-free, zero addr VALU. Mask weights
// (additive, log2 domain) in LDS, folded into QK acc init. One barrier/tile.
__global__ __launch_bounds__(128, 2) void flash_attn_split(
    const bf16_t* __restrict__ q, const bf16_t* __restrict__ kc,
    const bf16_t* __restrict__ vct, const float* __restrict__ mask,
    float* __restrict__ part_acc, float* __restrict__ part_l) {
  // XCD-affinity decode (1152 = 8 XCDs x 144 logical slots)
  const int bid = blockIdx.x;
  const int logical = (bid & 7) * 144 + (bid >> 3);
  const int z = logical / 72;        // 0..15, z-major: 2 chunks per XCD
  const int rem = logical - z * 72;  // 0..71
  const int h = rem / 6;
  const int qt = rem - h * 6;
  const int b = z >> 3, c = z & 7;

  const int tid = threadIdx.x;
  const int w = tid >> 6, lane = tid & 63, l31 = lane & 31, h5 = lane >> 5;

  __shared__ __align__(16) bf16_t kc_s[2][64 * 64];  // K dbuf, fragment-major
  __shared__ __align__(16) bf16_t vt_s[2][64 * 64];  // V dbuf, fragment-major
  __shared__ float w_all[KCHUNK];                    // additive mask (log2)

  const bf16_t* kcb = kc + (size_t)b * 589824;
  const bf16_t* vtb = vct + (size_t)b * 589824;
  const float* mkb = mask + b * 9216;
  const int k00 = c * KCHUNK;
  const int T0 = c * (KCHUNK / 64);  // global 64-key tile index base

  // Q B-frags, held for the whole kernel
  const int q0 = qt * 128 + w * 64;
  bf16x8 qf[2][4];
#pragma unroll
  for (int nb = 0; nb < 2; ++nb) {
    const bf16_t* qp =
        q + ((size_t)((b * 12 + h) * 768 + q0 + nb * 32 + l31) << 6) + h5 * 8;
#pragma unroll
    for (int kd = 0; kd < 4; ++kd) qf[nb][kd] = *(const bf16x8*)(qp + kd * 16);
  }

  // additive mask weights for the whole 1152-key chunk, once
  for (int i = tid; i < KCHUNK; i += 128)
    w_all[i] = fmaf(mkb[k00 + i], LOG2E, -SHIFT_C);

  // linear DMA staging: wave 0 -> K tile, wave 1 -> V tile (8x 1KB each)
  auto stage = [&](int t, int buf) {
    const int T = T0 + t;
    const char* ksrc = (const char*)(kcb + ((size_t)T << 12));
    const char* vsrc = (const char*)(vtb + ((size_t)T << 12));
#pragma unroll
    for (int i = 0; i < 8; ++i) {
      const int off = (i * 64 + lane) * 16;  // byte offset 0..8191
      if (w == 0)
        async_copy16(ksrc + off, (char*)&kc_s[buf][0] + off);
      else
        async_copy16(vsrc + off, (char*)&vt_s[buf][0] + off);
    }
  };

  stage(0, 0);

  f32x16 o[2][2];
#pragma unroll
  for (int nb = 0; nb < 2; ++nb)
#pragma unroll
    for (int md = 0; md < 2; ++md)
#pragma unroll
      for (int r = 0; r < 16; ++r) o[nb][md][r] = 0.f;
  float rsum[2] = {0.f, 0.f};

  const int lb = lane << 4;  // per-lane byte offset within a fragment

  for (int t = 0; t < KCHUNK / 64; ++t) {
    const int cur = t & 1;
    __syncthreads();  // drains DMA for buf[cur] (+ w_all on t=0)
    if (t + 1 < KCHUNK / 64) stage(t + 1, cur ^ 1);

    const char* kcS = (const char*)&kc_s[cur][0];
    const char* vtS = (const char*)&vt_s[cur][0];
    const float* wt = w_all + t * 64;

#pragma unroll
    for (int mb = 0; mb < 2; ++mb) {  // 32-key block
      bf16x8 ka[4];
#pragma unroll
      for (int kd = 0; kd < 4; ++kd)
        ka[kd] = *(const bf16x8*)(kcS + ((mb * 4 + kd) << 10) + lb);
      bf16x8 va[2][2];
#pragma unroll
      for (int md = 0; md < 2; ++md)
#pragma unroll
        for (int tt = 0; tt < 2; ++tt)
          va[md][tt] = *(const bf16x8*)(vtS + (((mb * 2 + tt) * 2 + md) << 10) + lb);
      float wv[16];
#pragma unroll
      for (int g = 0; g < 4; ++g) {
        const float4 t4 = *(const float4*)(wt + mb * 32 + h5 * 4 + g * 8);
        wv[g * 4 + 0] = t4.x; wv[g * 4 + 1] = t4.y;
        wv[g * 4 + 2] = t4.z; wv[g * 4 + 3] = t4.w;
      }
#pragma unroll
      for (int nb = 0; nb < 2; ++nb) {
        f32x16 s;
#pragma unroll
        for (int r = 0; r < 16; ++r) s[r] = wv[r];  // mask folded into acc init
#pragma unroll
        for (int kd = 0; kd < 4; ++kd) s = MFMA32(ka[kd], qf[nb][kd], s);
        bf16x8 pb0, pb1;
#pragma unroll
        for (int r = 0; r < 8; ++r) {
          const float pv = __builtin_amdgcn_exp2f(s[r]);
          rsum[nb] += pv;
          pb0[r] = (bf16_t)pv;
        }
#pragma unroll
        for (int r = 0; r < 8; ++r) {
          const float pv = __builtin_amdgcn_exp2f(s[8 + r]);
          rsum[nb] += pv;
          pb1[r] = (bf16_t)pv;
        }
#pragma unroll
        for (int md = 0; md < 2; ++md) {
          o[nb][md] = MFMA32(va[md][0], pb0, o[nb][md]);
          o[nb][md] = MFMA32(va[md][1], pb1, o[nb][md]);
        }
      }
    }
  }

  const float l0 = rsum[0] + __shfl_xor(rsum[0], 32);
  const float l1 = rsum[1] + __shfl_xor(rsum[1], 32);

  const int pidx = ((b * 12 + h) * 6 + qt) * NSPLIT + c;
  float* pacc = part_acc + (size_t)pidx * 8192;
#pragma unroll
  for (int nb = 0; nb < 2; ++nb) {
    const int ql = w * 64 + nb * 32 + l31;
#pragma unroll
    for (int md = 0; md < 2; ++md)
#pragma unroll
      for (int g = 0; g < 4; ++g) {
        float4 v;
        v.x = o[nb][md][g * 4 + 0];
        v.y = o[nb][md][g * 4 + 1];
        v.z = o[nb][md][g * 4 + 2];
        v.w = o[nb][md][g * 4 + 3];
        *(float4*)(pacc + (size_t)ql * 64 + md * 32 + h5 * 4 + g * 8) = v;
      }
  }
  if (h5 == 0) {
    part_l[(size_t)pidx * 128 + w * 64 + l31] = l0;
    part_l[(size_t)pidx * 128 + w * 64 + 32 + l31] = l1;
  }
}

// ---------------- combine split-K partials, normalize, gate, write out -----
// 576 blocks x 256 threads: each block handles 32 q-rows. Pure-BW kernel.
__global__ __launch_bounds__(256) void flash_combine(
    const float* __restrict__ part_acc, const float* __restrict__ part_l,
    const float* __restrict__ gate, float* __restrict__ out) {
  const int q32 = blockIdx.x, h = blockIdx.y, b = blockIdx.z;  // grid (24,12,2)
  const int tid = threadIdx.x;
  const int row = tid >> 3, dseg = tid & 7;  // 32 rows, 8 d-elems per thread
  const int s = q32 * 32 + row;              // global q-row 0..767
  const int qt = s >> 7;                     // 128-row part tile
  const int roff = s & 127;
  const int base = ((b * 12 + h) * 6 + qt) * NSPLIT;

  float L = 0.f;
#pragma unroll
  for (int ci = 0; ci < NSPLIT; ++ci) L += part_l[(size_t)(base + ci) * 128 + roff];

  f32x4 a0 = {0.f, 0.f, 0.f, 0.f}, a1 = {0.f, 0.f, 0.f, 0.f};
#pragma unroll
  for (int ci = 0; ci < NSPLIT; ++ci) {
    const float* p = part_acc + (size_t)(base + ci) * 8192 + roff * 64 + dseg * 8;
    const float4 v0 = *(const float4*)p;
    const float4 v1 = *(const float4*)(p + 4);
    a0[0] += v0.x; a0[1] += v0.y; a0[2] += v0.z; a0[3] += v0.w;
    a1[0] += v1.x; a1[1] += v1.y; a1[2] += v1.z; a1[3] += v1.w;
  }
  const float g = 1.f / (1.f + expf(-gate[h]));
  const float sc = g / L;
  float* op = out + ((size_t)((b * 768 + s) * 12 + h) << 6) + dseg * 8;
  float4 w0, w1;
  w0.x = a0[0] * sc; w0.y = a0[1] * sc; w0.z = a0[2] * sc; w0.w = a0[3] * sc;
  w1.x = a1[0] * sc; w1.y = a1[1] * sc; w1.z = a1[2] * sc; w1.w = a1[3] * sc;
  *(float4*)op = w0;
  *(float4*)(op + 4) = w1;
}

extern "C" void kernel_launch(void* const* d_in, const int* in_sizes, int n_in,
                              void* d_out, int out_size, void* d_ws, size_t ws_size,
                              hipStream_t stream) {
  const float* hid  = (const float*)d_in[0];
  const float* mask = (const float*)d_in[1];
  const float* Wq   = (const float*)d_in[2];
  const float* bq   = (const float*)d_in[3];
  const float* Wk   = (const float*)d_in[4];
  const float* bk   = (const float*)d_in[5];
  const float* Wv   = (const float*)d_in[6];
  const float* bv   = (const float*)d_in[7];
  const float* gate = (const float*)d_in[8];
  const float* memk = (const float*)d_in[9];
  const float* memv = (const float*)d_in[10];
  float* out = (float*)d_out;

  // workspace layout (~53.7 MB total). hidb/memkb/memvb alias the part_acc
  // region: they are consumed by gemm_qkv/gemm_mem, which complete before
  // flash_attn_split overwrites part_acc (same stream, sequential).
  char* ws = (char*)d_ws;
  bf16_t* wqkvT    = (bf16_t*)(ws);             // [2304][768] bf16
  bf16_t* qb       = (bf16_t*)(ws + 3538944);   // q [2][12][768][64] bf16
  bf16_t* ktvt     = (bf16_t*)(ws + 5898240);   // [1536][1536] bf16
  bf16_t* kcw      = (bf16_t*)(ws + 10616832);  // kc fragment-major, per b
  bf16_t* vct      = (bf16_t*)(ws + 12976128);  // vc^T fragment-major, per b
  float*  part_acc = (float*)(ws + 15335424);   // [1152][128][64] fp32
  float*  part_l   = (float*)(ws + 53084160);   // [1152][128] fp32
  bf16_t* hidb     = (bf16_t*)(ws + 15335424);  // [2][768][768] bf16 (alias)
  bf16_t* memkb    = (bf16_t*)(ws + 17694720);  // [12][768][768] bf16 (alias)
  bf16_t* memvb    = (bf16_t*)(ws + 31850496);  // [12][768][768] bf16 (alias)

  transpose_cvt3<<<dim3(24, 24, 3), dim3(32, 8), 0, stream>>>(Wq, Wk, Wv, wqkvT);
  cvt_inputs<<<dim3(1920), 256, 0, stream>>>(hid, memk, memv, hidb, memkb, memvb);
  gemm_qkv<<<dim3(12, 36), 256, 0, stream>>>(hidb, wqkvT, bq, bk, bv, qb, ktvt);
  gemm_mem<<<dim3(6, 2, 24), 256, 0, stream>>>(memkb, memvb, ktvt, kcw, vct);
  flash_attn_split<<<dim3(1152), 128, 0, stream>>>(qb, kcw, vct, mask,
                                                   part_acc, part_l);
  flash_combine<<<dim3(24, 12, 2), 256, 0, stream>>>(part_acc, part_l, gate, out);
}

// Round 14
// 212.076 us; speedup vs baseline: 1.0416x; 1.0035x over previous
//
#include <hip/hip_runtime.h>
#include <hip/hip_bf16.h>

// B=2, S=768, H=768, NH=12, D=64, NKEY=9216. Output fp32 [B][S][NH][D].
// Round 21: launch consolidation. r20 proved the ~146us periphery is not
// GEMM-BW/VALU-bound (bf16-izing was a wash, tile changes were a wash) --
// it's launch boundaries + under-filled dispatches (gemm_mem 288 blocks,
// Q-proj 144, six serialized kernels). This round: (1) prep = transpose +
// cvt_inputs fused (one streaming launch); (2) gemm_kv = ktvt projection
// alone (the only gemm_mem dependency); (3) gemm_mem_q = gemm_mem + the
// independent Q-projection co-dispatched (432 blocks fill the machine).
// All inner loops/epilogues byte-identical to r20; flash r18 verbatim.

typedef __bf16 bf16_t;
typedef __bf16 bf16x4 __attribute__((ext_vector_type(4)));
typedef __bf16 bf16x8 __attribute__((ext_vector_type(8)));
typedef float f32x4 __attribute__((ext_vector_type(4)));
typedef float f32x16 __attribute__((ext_vector_type(16)));
typedef unsigned long long u64;

#define MFMA16(a, b, c) __builtin_amdgcn_mfma_f32_16x16x32_bf16((a), (b), (c), 0, 0, 0)
#define MFMA32(a, b, c) __builtin_amdgcn_mfma_f32_32x32x16_bf16((a), (b), (c), 0, 0, 0)
#define LOG2E 1.44269504088896340736f
#define SCALE_Q 0.18033688011112042f /* (1/8) * log2(e) */
#define SHIFT_C 8.0f                 /* fixed softmax shift (base-2 units) */
#define NSPLIT 8
#define KCHUNK 1152 /* 9216/8, 18 tiles of 64 */

typedef __attribute__((address_space(3))) unsigned int lds_uint;
typedef const __attribute__((address_space(1))) unsigned int glob_uint;
__device__ __forceinline__ void async_copy16(const void* g, void* l) {
  __builtin_amdgcn_global_load_lds((glob_uint*)g, (lds_uint*)l, 16, 0, 0);
}

// ---------------- prep: W transpose+cvt (blocks 0..1727) ----------------
//                  + hid/memk/memv fp32->bf16 cvt (blocks 1728..3647) ----
__global__ __launch_bounds__(256) void prep(const float* __restrict__ Wq,
                                            const float* __restrict__ Wk,
                                            const float* __restrict__ Wv,
                                            bf16_t* __restrict__ Wt,
                                            const float* __restrict__ hid,
                                            const float* __restrict__ memk,
                                            const float* __restrict__ memv,
                                            bf16_t* __restrict__ hidb,
                                            bf16_t* __restrict__ memkb,
                                            bf16_t* __restrict__ memvb) {
  const int tid = threadIdx.x;
  if (blockIdx.x < 1728) {
    // transpose part: decode (bx, by, z) from blockIdx.x; threads (32,8)
    __shared__ float t[32][33];
    const int bidx = blockIdx.x;
    const int bxi = bidx % 24, byi = (bidx / 24) % 24, z = bidx / 576;
    const float* W = (z == 0) ? Wq : (z == 1) ? Wk : Wv;
    bf16_t* o = Wt + (size_t)z * 589824;
    const int bx = bxi * 32, by = byi * 32;
    const int tx = tid & 31, ty = tid >> 5;
#pragma unroll
    for (int i = 0; i < 32; i += 8) t[ty + i][tx] = W[(bx + ty + i) * 768 + by + tx];
    __syncthreads();
#pragma unroll
    for (int i = 0; i < 32; i += 8)
      o[(by + ty + i) * 768 + bx + tx] = (bf16_t)t[tx][ty + i];
  } else {
    // cvt part: grid-stride over float4s of hid, memk, memv
    const int NH4 = 1179648 / 4;
    const int NM4 = 7077888 / 4;
    const int TOT = NH4 + 2 * NM4;
    const int nb = gridDim.x - 1728;
    for (int i = (blockIdx.x - 1728) * 256 + tid; i < TOT; i += nb * 256) {
      const float* s;
      bf16_t* d;
      int off;
      if (i < NH4) {
        s = hid; d = hidb; off = i;
      } else if (i < NH4 + NM4) {
        s = memk; d = memkb; off = i - NH4;
      } else {
        s = memv; d = memvb; off = i - NH4 - NM4;
      }
      const float4 v = *(const float4*)(s + (size_t)off * 4);
      bf16x4 o;
      o[0] = (bf16_t)v.x; o[1] = (bf16_t)v.y;
      o[2] = (bf16_t)v.z; o[3] = (bf16_t)v.w;
      *(bf16x4*)(d + (size_t)off * 4) = o;
    }
  }
}

// ---------------- canonical C[M][N] = A[M][K] * B[N][K]^T, bf16 MFMA --------
// Double-buffered LDS, one barrier per 64-deep K slab, register prefetch.
template <int BM, int BN, typename EPI>
__device__ __forceinline__ void gemm_core(char* __restrict__ smem,
                                          const bf16_t* __restrict__ Ap, int lda,
                                          const bf16_t* __restrict__ Bp, int ldb,
                                          int K, int m0, int n0, EPI epi) {
  constexpr int MT = BM / 32;
  constexpr int NT = BN / 32;
  constexpr int AC = BM * 8 / 256;  // 16B chunks per thread (A)
  constexpr int BC = BN * 8 / 256;
  constexpr int HALF = (BM + BN) * 144;

  const int tid = threadIdx.x;
  const int lane = tid & 63;
  const int w = tid >> 6;
  const int l15 = lane & 15, quad = lane >> 4;
  const int wm = (w & 1) * (BM / 2);
  const int wn = (w >> 1) * (BN / 2);

  uint4 pa[AC], pb[BC];

  auto loadA = [&](int kk) {
#pragma unroll
    for (int i = 0; i < AC; ++i) {
      const int cidx = tid + i * 256, r = cidx >> 3, ch = cidx & 7;
      pa[i] = *(const uint4*)(Ap + (size_t)(m0 + r) * lda + kk + ch * 8);
    }
  };
  auto loadB = [&](int kk) {
#pragma unroll
    for (int i = 0; i < BC; ++i) {
      const int cidx = tid + i * 256, r = cidx >> 3, ch = cidx & 7;
      pb[i] = *(const uint4*)(Bp + (size_t)(n0 + r) * ldb + kk + ch * 8);
    }
  };
  auto store = [&](char* base) {
    char* sA = base;
    char* sB = base + BM * 144;
#pragma unroll
    for (int i = 0; i < AC; ++i) {
      const int cidx = tid + i * 256, r = cidx >> 3, ch = cidx & 7;
      *(uint4*)(sA + r * 144 + ch * 16) = pa[i];
    }
#pragma unroll
    for (int i = 0; i < BC; ++i) {
      const int cidx = tid + i * 256, r = cidx >> 3, ch = cidx & 7;
      *(uint4*)(sB + r * 144 + ch * 16) = pb[i];
    }
  };

  const f32x4 fzero = {0.f, 0.f, 0.f, 0.f};
  f32x4 acc[MT][NT];
#pragma unroll
  for (int i = 0; i < MT; ++i)
#pragma unroll
    for (int j = 0; j < NT; ++j) acc[i][j] = fzero;

  const int NS = K / 64;
  loadA(0);
  loadB(0);
  store(smem);

  for (int t = 0; t < NS; ++t) {
    char* base = smem + (t & 1) * HALF;
    char* sA = base;
    char* sB = base + BM * 144;
    __syncthreads();
    if (t + 1 < NS) {
      loadA((t + 1) * 64);
      loadB((t + 1) * 64);
    }
#pragma unroll
    for (int ks = 0; ks < 2; ++ks) {
      bf16x8 af[MT], bfr[NT];
#pragma unroll
      for (int i = 0; i < MT; ++i)
        af[i] = *(const bf16x8*)(sA + (wm + i * 16 + l15) * 144 + ks * 64 + quad * 16);
#pragma unroll
      for (int j = 0; j < NT; ++j)
        bfr[j] = *(const bf16x8*)(sB + (wn + j * 16 + l15) * 144 + ks * 64 + quad * 16);
#pragma unroll
      for (int i = 0; i < MT; ++i)
#pragma unroll
        for (int j = 0; j < NT; ++j) acc[i][j] = MFMA16(af[i], bfr[j], acc[i][j]);
    }
    if (t + 1 < NS) store(smem + ((t + 1) & 1) * HALF);
  }
#pragma unroll
  for (int i = 0; i < MT; ++i)
#pragma unroll
    for (int j = 0; j < NT; ++j)
#pragma unroll
      for (int p = 0; p < 4; ++p)
        epi(m0 + wm + i * 16 + quad * 4 + p, n0 + wn + j * 16 + l15, acc[i][j][p]);
}

// K^T/V^T projection (feeds gemm_mem_q). 128x64 tiles, grid (12,24).
__global__ __launch_bounds__(256) void gemm_kv(const bf16_t* __restrict__ hidb,
                                               const bf16_t* __restrict__ wT,
                                               const float* __restrict__ bk,
                                               const float* __restrict__ bv,
                                               bf16_t* __restrict__ ktvt) {
  __shared__ __align__(16) char smem[2 * (128 + 64) * 144];
  const int m0 = blockIdx.x * 128, n0 = blockIdx.y * 64;
  auto epi = [=](int m, int n, float v) {
    const float bias = (m < 768) ? bk[m] : bv[m - 768];
    ktvt[(size_t)m * 1536 + n] = (bf16_t)(v + bias);
  };
  gemm_core<128, 64>(smem, wT + 589824, 768, hidb, 768, 768, m0, n0, epi);
}

// Memory GEMMs + Q-projection co-dispatched. Grid (6,3,24):
//   y==0: kc = memk[h] @ k[b,h]   (128x64 tiles, fragment-major out)
//   y==1: vct = v^T[b,h] @ memv[h] (64x128 tiles, fragment-major out)
//   y==2: Q-projection (128x64 tiles; idx = z*6+x -> (m,n) of 12x12)
// Fragment-major layouts (r8/r16-verified):
//  kcF:  elem = ((T*2+mb)*4+kd)*512 + (h5*32+l31)*8 + j
//  vctF: elem = (((T*2+mb)*2+tt)*2+md)*512 + (h5*32+l31)*8 + u*4+j
__global__ __launch_bounds__(256) void gemm_mem_q(
    const bf16_t* __restrict__ memkb, const bf16_t* __restrict__ memvb,
    const bf16_t* __restrict__ ktvt, const bf16_t* __restrict__ hidb,
    const bf16_t* __restrict__ wT, const float* __restrict__ bq,
    bf16_t* __restrict__ kc, bf16_t* __restrict__ vct,
    bf16_t* __restrict__ q) {
  __shared__ __align__(16) char smem[2 * (128 + 64) * 144];
  const int z = blockIdx.z, b = z / 12, h = z - (z / 12) * 12;
  if (blockIdx.y == 0) {
    const int m0 = blockIdx.x * 128;
    const bf16_t* A = memkb + (size_t)h * 589824;
    const bf16_t* B = ktvt + (size_t)(h * 64) * 1536 + b * 768;
    bf16_t* outp = kc + (size_t)b * 589824;
    auto epi = [=](int m, int n, float v) {
      const int gk = h * 768 + m;  // global key index
      const int T = gk >> 6, mbk = (gk >> 5) & 1, l31k = gk & 31;
      const int kd = n >> 4, hh = (n >> 3) & 1, j = n & 7;
      outp[(((size_t)(T * 2 + mbk) * 4 + kd) << 9) + ((hh * 32 + l31k) << 3) + j] =
          (bf16_t)v;
    };
    gemm_core<128, 64>(smem, A, 768, B, 1536, 768, m0, 0, epi);
  } else if (blockIdx.y == 1) {
    const int n0 = blockIdx.x * 128;
    const bf16_t* A = ktvt + (size_t)(768 + h * 64) * 1536 + b * 768;
    const bf16_t* B = memvb + (size_t)h * 589824;
    bf16_t* outp = vct + (size_t)b * 589824;
    auto epi = [=](int m, int n, float v) {
      const int gk = h * 768 + n;  // global key index, m = d
      const int T = gk >> 6, mbv = (gk >> 5) & 1, tt = (gk >> 4) & 1;
      const int u = (gk >> 3) & 1, hh = (gk >> 2) & 1, j = gk & 3;
      const int md = m >> 5, l31v = m & 31;
      outp[((((size_t)(T * 2 + mbv) * 2 + tt) * 2 + md) << 9) +
           ((hh * 32 + l31v) << 3) + u * 4 + j] = (bf16_t)v;
    };
    gemm_core<64, 128>(smem, A, 1536, B, 768, 768, 0, n0, epi);
  } else {
    // Q-projection: 144 blocks = z(24) x x(6); idx -> (m-tile, n-tile) 12x12
    const int idx = z * 6 + blockIdx.x;
    const int m0 = (idx % 12) * 128, n0 = (idx / 12) * 64;
    auto epi = [=](int m, int n, float v) {
      const int bb = m / 768, s = m - bb * 768;
      const int hh = n >> 6, d = n & 63;
      q[((size_t)((bb * 12 + hh) * 768 + s) << 6) + d] =
          (bf16_t)((v + bq[n]) * SCALE_Q);
    };
    gemm_core<128, 64>(smem, hidb, 768, wT, 768, 768, m0, n0, epi);
  }
}

// ---------------- flash attention, split-K, 32x32 MFMA, transposed-S -------
// r18 VERBATIM (65.7us verified). 128-thread blocks (2 waves x 64 q-rows).
// 1-D grid 1152 with XCD-affinity swizzle (FETCH 21->7.4MB). K/V fragment-
// major: tile T = contiguous 8KB, staged via LINEAR global_load_lds DMA
// double-buffer (wave 0 -> K, wave 1 -> V; 8x 1KB). LDS fragment reads at
// frag*1KB + lane*16: conflict-free, zero addr VALU. Mask weights
// (additive, log2 domain) in LDS, folded into QK acc init. One barrier/tile.
__global__ __launch_bounds__(128, 2) void flash_attn_split(
    const bf16_t* __restrict__ q, const bf16_t* __restrict__ kc,
    const bf16_t* __restrict__ vct, const float* __restrict__ mask,
    float* __restrict__ part_acc, float* __restrict__ part_l) {
  // XCD-affinity decode (1152 = 8 XCDs x 144 logical slots)
  const int bid = blockIdx.x;
  const int logical = (bid & 7) * 144 + (bid >> 3);
  const int z = logical / 72;        // 0..15, z-major: 2 chunks per XCD
  const int rem = logical - z * 72;  // 0..71
  const int h = rem / 6;
  const int qt = rem - h * 6;
  const int b = z >> 3, c = z & 7;

  const int tid = threadIdx.x;
  const int w = tid >> 6, lane = tid & 63, l31 = lane & 31, h5 = lane >> 5;

  __shared__ __align__(16) bf16_t kc_s[2][64 * 64];  // K dbuf, fragment-major
  __shared__ __align__(16) bf16_t vt_s[2][64 * 64];  // V dbuf, fragment-major
  __shared__ float w_all[KCHUNK];                    // additive mask (log2)

  const bf16_t* kcb = kc + (size_t)b * 589824;
  const bf16_t* vtb = vct + (size_t)b * 589824;
  const float* mkb = mask + b * 9216;
  const int k00 = c * KCHUNK;
  const int T0 = c * (KCHUNK / 64);  // global 64-key tile index base

  // Q B-frags, held for the whole kernel
  const int q0 = qt * 128 + w * 64;
  bf16x8 qf[2][4];
#pragma unroll
  for (int nb = 0; nb < 2; ++nb) {
    const bf16_t* qp =
        q + ((size_t)((b * 12 + h) * 768 + q0 + nb * 32 + l31) << 6) + h5 * 8;
#pragma unroll
    for (int kd = 0; kd < 4; ++kd) qf[nb][kd] = *(const bf16x8*)(qp + kd * 16);
  }

  // additive mask weights for the whole 1152-key chunk, once
  for (int i = tid; i < KCHUNK; i += 128)
    w_all[i] = fmaf(mkb[k00 + i], LOG2E, -SHIFT_C);

  // linear DMA staging: wave 0 -> K tile, wave 1 -> V tile (8x 1KB each)
  auto stage = [&](int t, int buf) {
    const int T = T0 + t;
    const char* ksrc = (const char*)(kcb + ((size_t)T << 12));
    const char* vsrc = (const char*)(vtb + ((size_t)T << 12));
#pragma unroll
    for (int i = 0; i < 8; ++i) {
      const int off = (i * 64 + lane) * 16;  // byte offset 0..8191
      if (w == 0)
        async_copy16(ksrc + off, (char*)&kc_s[buf][0] + off);
      else
        async_copy16(vsrc + off, (char*)&vt_s[buf][0] + off);
    }
  };

  stage(0, 0);

  f32x16 o[2][2];
#pragma unroll
  for (int nb = 0; nb < 2; ++nb)
#pragma unroll
    for (int md = 0; md < 2; ++md)
#pragma unroll
      for (int r = 0; r < 16; ++r) o[nb][md][r] = 0.f;
  float rsum[2] = {0.f, 0.f};

  const int lb = lane << 4;  // per-lane byte offset within a fragment

  for (int t = 0; t < KCHUNK / 64; ++t) {
    const int cur = t & 1;
    __syncthreads();  // drains DMA for buf[cur] (+ w_all on t=0)
    if (t + 1 < KCHUNK / 64) stage(t + 1, cur ^ 1);

    const char* kcS = (const char*)&kc_s[cur][0];
    const char* vtS = (const char*)&vt_s[cur][0];
    const float* wt = w_all + t * 64;

#pragma unroll
    for (int mb = 0; mb < 2; ++mb) {  // 32-key block
      bf16x8 ka[4];
#pragma unroll
      for (int kd = 0; kd < 4; ++kd)
        ka[kd] = *(const bf16x8*)(kcS + ((mb * 4 + kd) << 10) + lb);
      bf16x8 va[2][2];
#pragma unroll
      for (int md = 0; md < 2; ++md)
#pragma unroll
        for (int tt = 0; tt < 2; ++tt)
          va[md][tt] = *(const bf16x8*)(vtS + (((mb * 2 + tt) * 2 + md) << 10) + lb);
      float wv[16];
#pragma unroll
      for (int g = 0; g < 4; ++g) {
        const float4 t4 = *(const float4*)(wt + mb * 32 + h5 * 4 + g * 8);
        wv[g * 4 + 0] = t4.x; wv[g * 4 + 1] = t4.y;
        wv[g * 4 + 2] = t4.z; wv[g * 4 + 3] = t4.w;
      }
#pragma unroll
      for (int nb = 0; nb < 2; ++nb) {
        f32x16 s;
#pragma unroll
        for (int r = 0; r < 16; ++r) s[r] = wv[r];  // mask folded into acc init
#pragma unroll
        for (int kd = 0; kd < 4; ++kd) s = MFMA32(ka[kd], qf[nb][kd], s);
        bf16x8 pb0, pb1;
#pragma unroll
        for (int r = 0; r < 8; ++r) {
          const float pv = __builtin_amdgcn_exp2f(s[r]);
          rsum[nb] += pv;
          pb0[r] = (bf16_t)pv;
        }
#pragma unroll
        for (int r = 0; r < 8; ++r) {
          const float pv = __builtin_amdgcn_exp2f(s[8 + r]);
          rsum[nb] += pv;
          pb1[r] = (bf16_t)pv;
        }
#pragma unroll
        for (int md = 0; md < 2; ++md) {
          o[nb][md] = MFMA32(va[md][0], pb0, o[nb][md]);
          o[nb][md] = MFMA32(va[md][1], pb1, o[nb][md]);
        }
      }
    }
  }

  const float l0 = rsum[0] + __shfl_xor(rsum[0], 32);
  const float l1 = rsum[1] + __shfl_xor(rsum[1], 32);

  const int pidx = ((b * 12 + h) * 6 + qt) * NSPLIT + c;
  float* pacc = part_acc + (size_t)pidx * 8192;
#pragma unroll
  for (int nb = 0; nb < 2; ++nb) {
    const int ql = w * 64 + nb * 32 + l31;
#pragma unroll
    for (int md = 0; md < 2; ++md)
#pragma unroll
      for (int g = 0; g < 4; ++g) {
        float4 v;
        v.x = o[nb][md][g * 4 + 0];
        v.y = o[nb][md][g * 4 + 1];
        v.z = o[nb][md][g * 4 + 2];
        v.w = o[nb][md][g * 4 + 3];
        *(float4*)(pacc + (size_t)ql * 64 + md * 32 + h5 * 4 + g * 8) = v;
      }
  }
  if (h5 == 0) {
    part_l[(size_t)pidx * 128 + w * 64 + l31] = l0;
    part_l[(size_t)pidx * 128 + w * 64 + 32 + l31] = l1;
  }
}

// ---------------- combine split-K partials, normalize, gate, write out -----
// 576 blocks x 256 threads: each block handles 32 q-rows. Pure-BW kernel.
__global__ __launch_bounds__(256) void flash_combine(
    const float* __restrict__ part_acc, const float* __restrict__ part_l,
    const float* __restrict__ gate, float* __restrict__ out) {
  const int q32 = blockIdx.x, h = blockIdx.y, b = blockIdx.z;  // grid (24,12,2)
  const int tid = threadIdx.x;
  const int row = tid >> 3, dseg = tid & 7;  // 32 rows, 8 d-elems per thread
  const int s = q32 * 32 + row;              // global q-row 0..767
  const int qt = s >> 7;                     // 128-row part tile
  const int roff = s & 127;
  const int base = ((b * 12 + h) * 6 + qt) * NSPLIT;

  float L = 0.f;
#pragma unroll
  for (int ci = 0; ci < NSPLIT; ++ci) L += part_l[(size_t)(base + ci) * 128 + roff];

  f32x4 a0 = {0.f, 0.f, 0.f, 0.f}, a1 = {0.f, 0.f, 0.f, 0.f};
#pragma unroll
  for (int ci = 0; ci < NSPLIT; ++ci) {
    const float* p = part_acc + (size_t)(base + ci) * 8192 + roff * 64 + dseg * 8;
    const float4 v0 = *(const float4*)p;
    const float4 v1 = *(const float4*)(p + 4);
    a0[0] += v0.x; a0[1] += v0.y; a0[2] += v0.z; a0[3] += v0.w;
    a1[0] += v1.x; a1[1] += v1.y; a1[2] += v1.z; a1[3] += v1.w;
  }
  const float g = 1.f / (1.f + expf(-gate[h]));
  const float sc = g / L;
  float* op = out + ((size_t)((b * 768 + s) * 12 + h) << 6) + dseg * 8;
  float4 w0, w1;
  w0.x = a0[0] * sc; w0.y = a0[1] * sc; w0.z = a0[2] * sc; w0.w = a0[3] * sc;
  w1.x = a1[0] * sc; w1.y = a1[1] * sc; w1.z = a1[2] * sc; w1.w = a1[3] * sc;
  *(float4*)op = w0;
  *(float4*)(op + 4) = w1;
}

extern "C" void kernel_launch(void* const* d_in, const int* in_sizes, int n_in,
                              void* d_out, int out_size, void* d_ws, size_t ws_size,
                              hipStream_t stream) {
  const float* hid  = (const float*)d_in[0];
  const float* mask = (const float*)d_in[1];
  const float* Wq   = (const float*)d_in[2];
  const float* bq   = (const float*)d_in[3];
  const float* Wk   = (const float*)d_in[4];
  const float* bk   = (const float*)d_in[5];
  const float* Wv   = (const float*)d_in[6];
  const float* bv   = (const float*)d_in[7];
  const float* gate = (const float*)d_in[8];
  const float* memk = (const float*)d_in[9];
  const float* memv = (const float*)d_in[10];
  float* out = (float*)d_out;

  // workspace layout (~53.7 MB total). hidb/memkb/memvb alias the part_acc
  // region: consumed by gemm_kv/gemm_mem_q, which complete before
  // flash_attn_split overwrites part_acc (same stream, sequential).
  char* ws = (char*)d_ws;
  bf16_t* wqkvT    = (bf16_t*)(ws);             // [2304][768] bf16
  bf16_t* qb       = (bf16_t*)(ws + 3538944);   // q [2][12][768][64] bf16
  bf16_t* ktvt     = (bf16_t*)(ws + 5898240);   // [1536][1536] bf16
  bf16_t* kcw      = (bf16_t*)(ws + 10616832);  // kc fragment-major, per b
  bf16_t* vct      = (bf16_t*)(ws + 12976128);  // vc^T fragment-major, per b
  float*  part_acc = (float*)(ws + 15335424);   // [1152][128][64] fp32
  float*  part_l   = (float*)(ws + 53084160);   // [1152][128] fp32
  bf16_t* hidb     = (bf16_t*)(ws + 15335424);  // [2][768][768] bf16 (alias)
  bf16_t* memkb    = (bf16_t*)(ws + 17694720);  // [12][768][768] bf16 (alias)
  bf16_t* memvb    = (bf16_t*)(ws + 31850496);  // [12][768][768] bf16 (alias)

  prep<<<dim3(3648), 256, 0, stream>>>(Wq, Wk, Wv, wqkvT, hid, memk, memv,
                                       hidb, memkb, memvb);
  gemm_kv<<<dim3(12, 24), 256, 0, stream>>>(hidb, wqkvT, bk, bv, ktvt);
  gemm_mem_q<<<dim3(6, 3, 24), 256, 0, stream>>>(memkb, memvb, ktvt, hidb,
                                                 wqkvT, bq, kcw, vct, qb);
  flash_attn_split<<<dim3(1152), 128, 0, stream>>>(qb, kcw, vct, mask,
                                                   part_acc, part_l);
  flash_combine<<<dim3(24, 12, 2), 256, 0, stream>>>(part_acc, part_l, gate, out);
}

// Round 15
// 210.943 us; speedup vs baseline: 1.0472x; 1.0054x over previous
//
#include <hip/hip_runtime.h>
#include <hip/hip_bf16.h>

// B=2, S=768, H=768, NH=12, D=64, NKEY=9216. Output fp32 [B][S][NH][D].
// Round 22: single-round residency for flash. Occupancy 13.5% decoded as
// two-round execution (LDS 37.4KB -> 4 blocks/CU capacity < 1152-block
// grid: 1024-round + 128-tail). Fix: mask table moves from LDS to
// registers (r10-verified loadmask pattern, loads for t+1 issued at
// bottom of tile t) -> LDS exactly 32768B -> 5 blocks/CU capacity -> all
// 1152 blocks co-resident, single round, zero tail. Flash math otherwise
// byte-identical to r18/r21 (fragment-major linear DMA dbuf, XCD-affinity
// swizzle, NSPLIT=8). Periphery identical to r21.

typedef __bf16 bf16_t;
typedef __bf16 bf16x4 __attribute__((ext_vector_type(4)));
typedef __bf16 bf16x8 __attribute__((ext_vector_type(8)));
typedef float f32x4 __attribute__((ext_vector_type(4)));
typedef float f32x16 __attribute__((ext_vector_type(16)));
typedef unsigned long long u64;

#define MFMA16(a, b, c) __builtin_amdgcn_mfma_f32_16x16x32_bf16((a), (b), (c), 0, 0, 0)
#define MFMA32(a, b, c) __builtin_amdgcn_mfma_f32_32x32x16_bf16((a), (b), (c), 0, 0, 0)
#define LOG2E 1.44269504088896340736f
#define SCALE_Q 0.18033688011112042f /* (1/8) * log2(e) */
#define SHIFT_C 8.0f                 /* fixed softmax shift (base-2 units) */
#define NSPLIT 8
#define KCHUNK 1152 /* 9216/8, 18 tiles of 64 */

typedef __attribute__((address_space(3))) unsigned int lds_uint;
typedef const __attribute__((address_space(1))) unsigned int glob_uint;
__device__ __forceinline__ void async_copy16(const void* g, void* l) {
  __builtin_amdgcn_global_load_lds((glob_uint*)g, (lds_uint*)l, 16, 0, 0);
}

// ---------------- prep: W transpose+cvt (blocks 0..1727) ----------------
//                  + hid/memk/memv fp32->bf16 cvt (blocks 1728..3647) ----
__global__ __launch_bounds__(256) void prep(const float* __restrict__ Wq,
                                            const float* __restrict__ Wk,
                                            const float* __restrict__ Wv,
                                            bf16_t* __restrict__ Wt,
                                            const float* __restrict__ hid,
                                            const float* __restrict__ memk,
                                            const float* __restrict__ memv,
                                            bf16_t* __restrict__ hidb,
                                            bf16_t* __restrict__ memkb,
                                            bf16_t* __restrict__ memvb) {
  const int tid = threadIdx.x;
  if (blockIdx.x < 1728) {
    // transpose part: decode (bx, by, z) from blockIdx.x; threads (32,8)
    __shared__ float t[32][33];
    const int bidx = blockIdx.x;
    const int bxi = bidx % 24, byi = (bidx / 24) % 24, z = bidx / 576;
    const float* W = (z == 0) ? Wq : (z == 1) ? Wk : Wv;
    bf16_t* o = Wt + (size_t)z * 589824;
    const int bx = bxi * 32, by = byi * 32;
    const int tx = tid & 31, ty = tid >> 5;
#pragma unroll
    for (int i = 0; i < 32; i += 8) t[ty + i][tx] = W[(bx + ty + i) * 768 + by + tx];
    __syncthreads();
#pragma unroll
    for (int i = 0; i < 32; i += 8)
      o[(by + ty + i) * 768 + bx + tx] = (bf16_t)t[tx][ty + i];
  } else {
    // cvt part: grid-stride over float4s of hid, memk, memv
    const int NH4 = 1179648 / 4;
    const int NM4 = 7077888 / 4;
    const int TOT = NH4 + 2 * NM4;
    const int nb = gridDim.x - 1728;
    for (int i = (blockIdx.x - 1728) * 256 + tid; i < TOT; i += nb * 256) {
      const float* s;
      bf16_t* d;
      int off;
      if (i < NH4) {
        s = hid; d = hidb; off = i;
      } else if (i < NH4 + NM4) {
        s = memk; d = memkb; off = i - NH4;
      } else {
        s = memv; d = memvb; off = i - NH4 - NM4;
      }
      const float4 v = *(const float4*)(s + (size_t)off * 4);
      bf16x4 o;
      o[0] = (bf16_t)v.x; o[1] = (bf16_t)v.y;
      o[2] = (bf16_t)v.z; o[3] = (bf16_t)v.w;
      *(bf16x4*)(d + (size_t)off * 4) = o;
    }
  }
}

// ---------------- canonical C[M][N] = A[M][K] * B[N][K]^T, bf16 MFMA --------
// Double-buffered LDS, one barrier per 64-deep K slab, register prefetch.
template <int BM, int BN, typename EPI>
__device__ __forceinline__ void gemm_core(char* __restrict__ smem,
                                          const bf16_t* __restrict__ Ap, int lda,
                                          const bf16_t* __restrict__ Bp, int ldb,
                                          int K, int m0, int n0, EPI epi) {
  constexpr int MT = BM / 32;
  constexpr int NT = BN / 32;
  constexpr int AC = BM * 8 / 256;  // 16B chunks per thread (A)
  constexpr int BC = BN * 8 / 256;
  constexpr int HALF = (BM + BN) * 144;

  const int tid = threadIdx.x;
  const int lane = tid & 63;
  const int w = tid >> 6;
  const int l15 = lane & 15, quad = lane >> 4;
  const int wm = (w & 1) * (BM / 2);
  const int wn = (w >> 1) * (BN / 2);

  uint4 pa[AC], pb[BC];

  auto loadA = [&](int kk) {
#pragma unroll
    for (int i = 0; i < AC; ++i) {
      const int cidx = tid + i * 256, r = cidx >> 3, ch = cidx & 7;
      pa[i] = *(const uint4*)(Ap + (size_t)(m0 + r) * lda + kk + ch * 8);
    }
  };
  auto loadB = [&](int kk) {
#pragma unroll
    for (int i = 0; i < BC; ++i) {
      const int cidx = tid + i * 256, r = cidx >> 3, ch = cidx & 7;
      pb[i] = *(const uint4*)(Bp + (size_t)(n0 + r) * ldb + kk + ch * 8);
    }
  };
  auto store = [&](char* base) {
    char* sA = base;
    char* sB = base + BM * 144;
#pragma unroll
    for (int i = 0; i < AC; ++i) {
      const int cidx = tid + i * 256, r = cidx >> 3, ch = cidx & 7;
      *(uint4*)(sA + r * 144 + ch * 16) = pa[i];
    }
#pragma unroll
    for (int i = 0; i < BC; ++i) {
      const int cidx = tid + i * 256, r = cidx >> 3, ch = cidx & 7;
      *(uint4*)(sB + r * 144 + ch * 16) = pb[i];
    }
  };

  const f32x4 fzero = {0.f, 0.f, 0.f, 0.f};
  f32x4 acc[MT][NT];
#pragma unroll
  for (int i = 0; i < MT; ++i)
#pragma unroll
    for (int j = 0; j < NT; ++j) acc[i][j] = fzero;

  const int NS = K / 64;
  loadA(0);
  loadB(0);
  store(smem);

  for (int t = 0; t < NS; ++t) {
    char* base = smem + (t & 1) * HALF;
    char* sA = base;
    char* sB = base + BM * 144;
    __syncthreads();
    if (t + 1 < NS) {
      loadA((t + 1) * 64);
      loadB((t + 1) * 64);
    }
#pragma unroll
    for (int ks = 0; ks < 2; ++ks) {
      bf16x8 af[MT], bfr[NT];
#pragma unroll
      for (int i = 0; i < MT; ++i)
        af[i] = *(const bf16x8*)(sA + (wm + i * 16 + l15) * 144 + ks * 64 + quad * 16);
#pragma unroll
      for (int j = 0; j < NT; ++j)
        bfr[j] = *(const bf16x8*)(sB + (wn + j * 16 + l15) * 144 + ks * 64 + quad * 16);
#pragma unroll
      for (int i = 0; i < MT; ++i)
#pragma unroll
        for (int j = 0; j < NT; ++j) acc[i][j] = MFMA16(af[i], bfr[j], acc[i][j]);
    }
    if (t + 1 < NS) store(smem + ((t + 1) & 1) * HALF);
  }
#pragma unroll
  for (int i = 0; i < MT; ++i)
#pragma unroll
    for (int j = 0; j < NT; ++j)
#pragma unroll
      for (int p = 0; p < 4; ++p)
        epi(m0 + wm + i * 16 + quad * 4 + p, n0 + wn + j * 16 + l15, acc[i][j][p]);
}

// K^T/V^T projection (feeds gemm_mem_q). 128x64 tiles, grid (12,24).
__global__ __launch_bounds__(256) void gemm_kv(const bf16_t* __restrict__ hidb,
                                               const bf16_t* __restrict__ wT,
                                               const float* __restrict__ bk,
                                               const float* __restrict__ bv,
                                               bf16_t* __restrict__ ktvt) {
  __shared__ __align__(16) char smem[2 * (128 + 64) * 144];
  const int m0 = blockIdx.x * 128, n0 = blockIdx.y * 64;
  auto epi = [=](int m, int n, float v) {
    const float bias = (m < 768) ? bk[m] : bv[m - 768];
    ktvt[(size_t)m * 1536 + n] = (bf16_t)(v + bias);
  };
  gemm_core<128, 64>(smem, wT + 589824, 768, hidb, 768, 768, m0, n0, epi);
}

// Memory GEMMs + Q-projection co-dispatched. Grid (6,3,24):
//   y==0: kc = memk[h] @ k[b,h]   (128x64 tiles, fragment-major out)
//   y==1: vct = v^T[b,h] @ memv[h] (64x128 tiles, fragment-major out)
//   y==2: Q-projection (128x64 tiles; idx = z*6+x -> (m,n) of 12x12)
// Fragment-major layouts (r8/r16-verified):
//  kcF:  elem = ((T*2+mb)*4+kd)*512 + (h5*32+l31)*8 + j
//  vctF: elem = (((T*2+mb)*2+tt)*2+md)*512 + (h5*32+l31)*8 + u*4+j
__global__ __launch_bounds__(256) void gemm_mem_q(
    const bf16_t* __restrict__ memkb, const bf16_t* __restrict__ memvb,
    const bf16_t* __restrict__ ktvt, const bf16_t* __restrict__ hidb,
    const bf16_t* __restrict__ wT, const float* __restrict__ bq,
    bf16_t* __restrict__ kc, bf16_t* __restrict__ vct,
    bf16_t* __restrict__ q) {
  __shared__ __align__(16) char smem[2 * (128 + 64) * 144];
  const int z = blockIdx.z, b = z / 12, h = z - (z / 12) * 12;
  if (blockIdx.y == 0) {
    const int m0 = blockIdx.x * 128;
    const bf16_t* A = memkb + (size_t)h * 589824;
    const bf16_t* B = ktvt + (size_t)(h * 64) * 1536 + b * 768;
    bf16_t* outp = kc + (size_t)b * 589824;
    auto epi = [=](int m, int n, float v) {
      const int gk = h * 768 + m;  // global key index
      const int T = gk >> 6, mbk = (gk >> 5) & 1, l31k = gk & 31;
      const int kd = n >> 4, hh = (n >> 3) & 1, j = n & 7;
      outp[(((size_t)(T * 2 + mbk) * 4 + kd) << 9) + ((hh * 32 + l31k) << 3) + j] =
          (bf16_t)v;
    };
    gemm_core<128, 64>(smem, A, 768, B, 1536, 768, m0, 0, epi);
  } else if (blockIdx.y == 1) {
    const int n0 = blockIdx.x * 128;
    const bf16_t* A = ktvt + (size_t)(768 + h * 64) * 1536 + b * 768;
    const bf16_t* B = memvb + (size_t)h * 589824;
    bf16_t* outp = vct + (size_t)b * 589824;
    auto epi = [=](int m, int n, float v) {
      const int gk = h * 768 + n;  // global key index, m = d
      const int T = gk >> 6, mbv = (gk >> 5) & 1, tt = (gk >> 4) & 1;
      const int u = (gk >> 3) & 1, hh = (gk >> 2) & 1, j = gk & 3;
      const int md = m >> 5, l31v = m & 31;
      outp[((((size_t)(T * 2 + mbv) * 2 + tt) * 2 + md) << 9) +
           ((hh * 32 + l31v) << 3) + u * 4 + j] = (bf16_t)v;
    };
    gemm_core<64, 128>(smem, A, 1536, B, 768, 768, 0, n0, epi);
  } else {
    // Q-projection: 144 blocks = z(24) x x(6); idx -> (m-tile, n-tile) 12x12
    const int idx = z * 6 + blockIdx.x;
    const int m0 = (idx % 12) * 128, n0 = (idx / 12) * 64;
    auto epi = [=](int m, int n, float v) {
      const int bb = m / 768, s = m - bb * 768;
      const int hh = n >> 6, d = n & 63;
      q[((size_t)((bb * 12 + hh) * 768 + s) << 6) + d] =
          (bf16_t)((v + bq[n]) * SCALE_Q);
    };
    gemm_core<128, 64>(smem, hidb, 768, wT, 768, 768, m0, n0, epi);
  }
}

// ---------------- flash attention, split-K, 32x32 MFMA, transposed-S -------
// 128-thread blocks (2 waves x 64 q-rows). 1-D grid 1152 with XCD-affinity
// swizzle (FETCH 21->7.4MB verified). K/V fragment-major: tile T =
// contiguous 8KB, staged via LINEAR global_load_lds DMA double-buffer
// (wave 0 -> K, wave 1 -> V; 8x 1KB). LDS fragment reads at frag*1KB +
// lane*16: conflict-free, zero addr VALU. MASK IN REGISTERS (r10-verified
// loadmask pattern): raw float4s for tile t+1 loaded at bottom of tile t;
// fmaf fold into QK acc init inside the tile body. LDS = exactly 32768B
// -> 5 blocks/CU capacity -> all 1152 blocks co-resident, single round.
__global__ __launch_bounds__(128, 2) void flash_attn_split(
    const bf16_t* __restrict__ q, const bf16_t* __restrict__ kc,
    const bf16_t* __restrict__ vct, const float* __restrict__ mask,
    float* __restrict__ part_acc, float* __restrict__ part_l) {
  // XCD-affinity decode (1152 = 8 XCDs x 144 logical slots)
  const int bid = blockIdx.x;
  const int logical = (bid & 7) * 144 + (bid >> 3);
  const int z = logical / 72;        // 0..15, z-major: 2 chunks per XCD
  const int rem = logical - z * 72;  // 0..71
  const int h = rem / 6;
  const int qt = rem - h * 6;
  const int b = z >> 3, c = z & 7;

  const int tid = threadIdx.x;
  const int w = tid >> 6, lane = tid & 63, l31 = lane & 31, h5 = lane >> 5;

  __shared__ __align__(16) bf16_t kc_s[2][64 * 64];  // K dbuf, fragment-major
  __shared__ __align__(16) bf16_t vt_s[2][64 * 64];  // V dbuf, fragment-major
  // LDS total = 32768 B exactly -> 5 blocks/CU

  const bf16_t* kcb = kc + (size_t)b * 589824;
  const bf16_t* vtb = vct + (size_t)b * 589824;
  const float* mkb = mask + b * 9216;
  const int k00 = c * KCHUNK;
  const int T0 = c * (KCHUNK / 64);  // global 64-key tile index base

  // Q B-frags, held for the whole kernel
  const int q0 = qt * 128 + w * 64;
  bf16x8 qf[2][4];
#pragma unroll
  for (int nb = 0; nb < 2; ++nb) {
    const bf16_t* qp =
        q + ((size_t)((b * 12 + h) * 768 + q0 + nb * 32 + l31) << 6) + h5 * 8;
#pragma unroll
    for (int kd = 0; kd < 4; ++kd) qf[nb][kd] = *(const bf16x8*)(qp + kd * 16);
  }

  // raw mask float4s for one tile (register-resident; folded after barrier)
  float4 mv[2][4];
  auto loadmask = [&](int t) {
    const float* wt = mkb + k00 + t * 64;
#pragma unroll
    for (int mb = 0; mb < 2; ++mb)
#pragma unroll
      for (int g = 0; g < 4; ++g)
        mv[mb][g] = *(const float4*)(wt + mb * 32 + h5 * 4 + g * 8);
  };

  // linear DMA staging: wave 0 -> K tile, wave 1 -> V tile (8x 1KB each)
  auto stage = [&](int t, int buf) {
    const int T = T0 + t;
    const char* ksrc = (const char*)(kcb + ((size_t)T << 12));
    const char* vsrc = (const char*)(vtb + ((size_t)T << 12));
#pragma unroll
    for (int i = 0; i < 8; ++i) {
      const int off = (i * 64 + lane) * 16;  // byte offset 0..8191
      if (w == 0)
        async_copy16(ksrc + off, (char*)&kc_s[buf][0] + off);
      else
        async_copy16(vsrc + off, (char*)&vt_s[buf][0] + off);
    }
  };

  loadmask(0);
  stage(0, 0);

  f32x16 o[2][2];
#pragma unroll
  for (int nb = 0; nb < 2; ++nb)
#pragma unroll
    for (int md = 0; md < 2; ++md)
#pragma unroll
      for (int r = 0; r < 16; ++r) o[nb][md][r] = 0.f;
  float rsum[2] = {0.f, 0.f};

  const int lb = lane << 4;  // per-lane byte offset within a fragment

  for (int t = 0; t < KCHUNK / 64; ++t) {
    const int cur = t & 1;
    __syncthreads();  // drains DMA for buf[cur]
    if (t + 1 < KCHUNK / 64) stage(t + 1, cur ^ 1);

    const char* kcS = (const char*)&kc_s[cur][0];
    const char* vtS = (const char*)&vt_s[cur][0];

#pragma unroll
    for (int mb = 0; mb < 2; ++mb) {  // 32-key block
      bf16x8 ka[4];
#pragma unroll
      for (int kd = 0; kd < 4; ++kd)
        ka[kd] = *(const bf16x8*)(kcS + ((mb * 4 + kd) << 10) + lb);
      bf16x8 va[2][2];
#pragma unroll
      for (int md = 0; md < 2; ++md)
#pragma unroll
        for (int tt = 0; tt < 2; ++tt)
          va[md][tt] = *(const bf16x8*)(vtS + (((mb * 2 + tt) * 2 + md) << 10) + lb);
      // additive mask init (log2 domain): s = mask*log2e - 8
      float wv[16];
#pragma unroll
      for (int g = 0; g < 4; ++g) {
        wv[g * 4 + 0] = fmaf(mv[mb][g].x, LOG2E, -SHIFT_C);
        wv[g * 4 + 1] = fmaf(mv[mb][g].y, LOG2E, -SHIFT_C);
        wv[g * 4 + 2] = fmaf(mv[mb][g].z, LOG2E, -SHIFT_C);
        wv[g * 4 + 3] = fmaf(mv[mb][g].w, LOG2E, -SHIFT_C);
      }
#pragma unroll
      for (int nb = 0; nb < 2; ++nb) {
        f32x16 s;
#pragma unroll
        for (int r = 0; r < 16; ++r) s[r] = wv[r];  // mask folded into acc init
#pragma unroll
        for (int kd = 0; kd < 4; ++kd) s = MFMA32(ka[kd], qf[nb][kd], s);
        bf16x8 pb0, pb1;
#pragma unroll
        for (int r = 0; r < 8; ++r) {
          const float pv = __builtin_amdgcn_exp2f(s[r]);
          rsum[nb] += pv;
          pb0[r] = (bf16_t)pv;
        }
#pragma unroll
        for (int r = 0; r < 8; ++r) {
          const float pv = __builtin_amdgcn_exp2f(s[8 + r]);
          rsum[nb] += pv;
          pb1[r] = (bf16_t)pv;
        }
#pragma unroll
        for (int md = 0; md < 2; ++md) {
          o[nb][md] = MFMA32(va[md][0], pb0, o[nb][md]);
          o[nb][md] = MFMA32(va[md][1], pb1, o[nb][md]);
        }
      }
    }
    if (t + 1 < KCHUNK / 64) loadmask(t + 1);  // lands before next use
  }

  const float l0 = rsum[0] + __shfl_xor(rsum[0], 32);
  const float l1 = rsum[1] + __shfl_xor(rsum[1], 32);

  const int pidx = ((b * 12 + h) * 6 + qt) * NSPLIT + c;
  float* pacc = part_acc + (size_t)pidx * 8192;
#pragma unroll
  for (int nb = 0; nb < 2; ++nb) {
    const int ql = w * 64 + nb * 32 + l31;
#pragma unroll
    for (int md = 0; md < 2; ++md)
#pragma unroll
      for (int g = 0; g < 4; ++g) {
        float4 v;
        v.x = o[nb][md][g * 4 + 0];
        v.y = o[nb][md][g * 4 + 1];
        v.z = o[nb][md][g * 4 + 2];
        v.w = o[nb][md][g * 4 + 3];
        *(float4*)(pacc + (size_t)ql * 64 + md * 32 + h5 * 4 + g * 8) = v;
      }
  }
  if (h5 == 0) {
    part_l[(size_t)pidx * 128 + w * 64 + l31] = l0;
    part_l[(size_t)pidx * 128 + w * 64 + 32 + l31] = l1;
  }
}

// ---------------- combine split-K partials, normalize, gate, write out -----
// 576 blocks x 256 threads: each block handles 32 q-rows. Pure-BW kernel.
__global__ __launch_bounds__(256) void flash_combine(
    const float* __restrict__ part_acc, const float* __restrict__ part_l,
    const float* __restrict__ gate, float* __restrict__ out) {
  const int q32 = blockIdx.x, h = blockIdx.y, b = blockIdx.z;  // grid (24,12,2)
  const int tid = threadIdx.x;
  const int row = tid >> 3, dseg = tid & 7;  // 32 rows, 8 d-elems per thread
  const int s = q32 * 32 + row;              // global q-row 0..767
  const int qt = s >> 7;                     // 128-row part tile
  const int roff = s & 127;
  const int base = ((b * 12 + h) * 6 + qt) * NSPLIT;

  float L = 0.f;
#pragma unroll
  for (int ci = 0; ci < NSPLIT; ++ci) L += part_l[(size_t)(base + ci) * 128 + roff];

  f32x4 a0 = {0.f, 0.f, 0.f, 0.f}, a1 = {0.f, 0.f, 0.f, 0.f};
#pragma unroll
  for (int ci = 0; ci < NSPLIT; ++ci) {
    const float* p = part_acc + (size_t)(base + ci) * 8192 + roff * 64 + dseg * 8;
    const float4 v0 = *(const float4*)p;
    const float4 v1 = *(const float4*)(p + 4);
    a0[0] += v0.x; a0[1] += v0.y; a0[2] += v0.z; a0[3] += v0.w;
    a1[0] += v1.x; a1[1] += v1.y; a1[2] += v1.z; a1[3] += v1.w;
  }
  const float g = 1.f / (1.f + expf(-gate[h]));
  const float sc = g / L;
  float* op = out + ((size_t)((b * 768 + s) * 12 + h) << 6) + dseg * 8;
  float4 w0, w1;
  w0.x = a0[0] * sc; w0.y = a0[1] * sc; w0.z = a0[2] * sc; w0.w = a0[3] * sc;
  w1.x = a1[0] * sc; w1.y = a1[1] * sc; w1.z = a1[2] * sc; w1.w = a1[3] * sc;
  *(float4*)op = w0;
  *(float4*)(op + 4) = w1;
}

extern "C" void kernel_launch(void* const* d_in, const int* in_sizes, int n_in,
                              void* d_out, int out_size, void* d_ws, size_t ws_size,
                              hipStream_t stream) {
  const float* hid  = (const float*)d_in[0];
  const float* mask = (const float*)d_in[1];
  const float* Wq   = (const float*)d_in[2];
  const float* bq   = (const float*)d_in[3];
  const float* Wk   = (const float*)d_in[4];
  const float* bk   = (const float*)d_in[5];
  const float* Wv   = (const float*)d_in[6];
  const float* bv   = (const float*)d_in[7];
  const float* gate = (const float*)d_in[8];
  const float* memk = (const float*)d_in[9];
  const float* memv = (const float*)d_in[10];
  float* out = (float*)d_out;

  // workspace layout (~53.7 MB total). hidb/memkb/memvb alias the part_acc
  // region: consumed by gemm_kv/gemm_mem_q, which complete before
  // flash_attn_split overwrites part_acc (same stream, sequential).
  char* ws = (char*)d_ws;
  bf16_t* wqkvT    = (bf16_t*)(ws);             // [2304][768] bf16
  bf16_t* qb       = (bf16_t*)(ws + 3538944);   // q [2][12][768][64] bf16
  bf16_t* ktvt     = (bf16_t*)(ws + 5898240);   // [1536][1536] bf16
  bf16_t* kcw      = (bf16_t*)(ws + 10616832);  // kc fragment-major, per b
  bf16_t* vct      = (bf16_t*)(ws + 12976128);  // vc^T fragment-major, per b
  float*  part_acc = (float*)(ws + 15335424);   // [1152][128][64] fp32
  float*  part_l   = (float*)(ws + 53084160);   // [1152][128] fp32
  bf16_t* hidb     = (bf16_t*)(ws + 15335424);  // [2][768][768] bf16 (alias)
  bf16_t* memkb    = (bf16_t*)(ws + 17694720);  // [12][768][768] bf16 (alias)
  bf16_t* memvb    = (bf16_t*)(ws + 31850496);  // [12][768][768] bf16 (alias)

  prep<<<dim3(3648), 256, 0, stream>>>(Wq, Wk, Wv, wqkvT, hid, memk, memv,
                                       hidb, memkb, memvb);
  gemm_kv<<<dim3(12, 24), 256, 0, stream>>>(hidb, wqkvT, bk, bv, ktvt);
  gemm_mem_q<<<dim3(6, 3, 24), 256, 0, stream>>>(memkb, memvb, ktvt, hidb,
                                                 wqkvT, bq, kcw, vct, qb);
  flash_attn_split<<<dim3(1152), 128, 0, stream>>>(qb, kcw, vct, mask,
                                                   part_acc, part_l);
  flash_combine<<<dim3(24, 12, 2), 256, 0, stream>>>(part_acc, part_l, gate, out);
}